// Round 1
// baseline (605.586 us; speedup 1.0000x reference)
//
#include <hip/hip_runtime.h>

typedef short short8 __attribute__((ext_vector_type(8)));
typedef float f32x4 __attribute__((ext_vector_type(4)));

#define SEQ 2048
#define QSCALE 0.18033688011112042f   // 0.125 * log2(e): softmax done in base 2
#define PSHIFT 20.0f                  // fixed softmax shift (cancels in O = acc/l)
#define EXP2(x) __builtin_amdgcn_exp2f(x)

// async global->LDS, 16B per lane; lds base must be wave-uniform
#define GLDS(g, l) __builtin_amdgcn_global_load_lds( \
    (const __attribute__((address_space(1))) unsigned int*)(g), \
    (__attribute__((address_space(3))) unsigned int*)(l), 16, 0, 0)

__device__ __forceinline__ unsigned short f2bf(float f) {
    unsigned int u = __builtin_bit_cast(unsigned int, f);
    unsigned int r = (u + 0x7fffu + ((u >> 16) & 1u)) >> 16;
    return (unsigned short)r;
}

// ---------------------------------------------------------------------------
// Batched weight transpose + fp32->bf16: 8 D x D weights in one launch.
// ---------------------------------------------------------------------------
__global__ __launch_bounds__(256)
void wtrans8_kernel(const float* w0, const float* w1, const float* w2, const float* w3,
                    const float* w4, const float* w5, const float* w6, const float* w7,
                    unsigned short* __restrict__ outbase)
{
    const float* Ws[8] = {w0, w1, w2, w3, w4, w5, w6, w7};
    const float* __restrict__ W = Ws[blockIdx.z];
    unsigned short* __restrict__ Wt = outbase + (size_t)blockIdx.z * 1024 * 1024;
    __shared__ float t[32][33];
    const int tx = threadIdx.x & 31;
    const int ty = threadIdx.x >> 5;
    const int nb = blockIdx.x * 32;
    const int kb = blockIdx.y * 32;
#pragma unroll
    for (int i = 0; i < 4; i++)
        t[ty + i * 8][tx] = W[(size_t)(kb + ty + i * 8) * 1024 + nb + tx];
    __syncthreads();
#pragma unroll
    for (int i = 0; i < 4; i++)
        Wt[(size_t)(nb + ty + i * 8) * 1024 + kb + tx] = f2bf(t[tx][ty + i * 8]);
}

// single weight transpose (for the two FFN shapes)
__global__ __launch_bounds__(256)
void wtrans_kernel(const float* __restrict__ W, unsigned short* __restrict__ Wt,
                   int Kd, int Nd)
{
    __shared__ float t[32][33];
    const int tx = threadIdx.x & 31;
    const int ty = threadIdx.x >> 5;
    const int nb = blockIdx.x * 32;
    const int kb = blockIdx.y * 32;
#pragma unroll
    for (int i = 0; i < 4; i++)
        t[ty + i * 8][tx] = W[(size_t)(kb + ty + i * 8) * Nd + nb + tx];
    __syncthreads();
#pragma unroll
    for (int i = 0; i < 4; i++)
        Wt[(size_t)(nb + ty + i * 8) * Kd + kb + tx] = f2bf(t[tx][ty + i * 8]);
}

// ---------------------------------------------------------------------------
// Elementwise fp32 -> bf16
// ---------------------------------------------------------------------------
__global__ __launch_bounds__(256)
void cvt_kernel(const float* __restrict__ in, unsigned short* __restrict__ out, int n)
{
    int i = (blockIdx.x * 256 + threadIdx.x) * 4;
    if (i < n) {
        float4 v = *(const float4*)(in + i);
        ushort4 o;
        o.x = f2bf(v.x); o.y = f2bf(v.y); o.z = f2bf(v.z); o.w = f2bf(v.w);
        *(ushort4*)(out + i) = o;
    }
}

// ---------------------------------------------------------------------------
// LayerNorm (torch-faithful: ddof=1, eps added to std). fp32 in -> bf16 out.
// ---------------------------------------------------------------------------
__global__ __launch_bounds__(256)
void ln_kernel(const float* __restrict__ x, const float* __restrict__ g,
               const float* __restrict__ bb, unsigned short* __restrict__ out)
{
    const int D = 1024;
    const int row = blockIdx.x;
    const float* xr = x + (size_t)row * D;
    float v[4];
    float s = 0.f, ss = 0.f;
#pragma unroll
    for (int i = 0; i < 4; i++) {
        v[i] = xr[threadIdx.x + i * 256];
        s += v[i];
        ss += v[i] * v[i];
    }
#pragma unroll
    for (int off = 1; off < 64; off <<= 1) {
        s  += __shfl_xor(s,  off, 64);
        ss += __shfl_xor(ss, off, 64);
    }
    __shared__ float red[8];
    const int wave = threadIdx.x >> 6;
    if ((threadIdx.x & 63) == 0) { red[wave] = s; red[4 + wave] = ss; }
    __syncthreads();
    s  = red[0] + red[1] + red[2] + red[3];
    ss = red[4] + red[5] + red[6] + red[7];
    float mean = s / D;
    float var  = fmaxf((ss - s * mean) / (D - 1), 0.f);
    float inv  = 1.f / (sqrtf(var) + 1e-6f);
#pragma unroll
    for (int i = 0; i < 4; i++) {
        int c = threadIdx.x + i * 256;
        out[(size_t)row * D + c] = f2bf(g[c] * (v[i] - mean) * inv + bb[c]);
    }
}

// ---------------------------------------------------------------------------
// Tiled MFMA GEMM (m97 structure): C[M,N] = A[M,K] @ Wt[N,K]^T + bias
// 128x128 tile, BK=32, unpadded LDS, global_load_lds 16B async staging.
// MODE 1: projection GEMM. Section = n0>>10: 0 -> Q (from A, scaled QSCALE,
//         head layout [B,H,S,64]); 1 -> K (from A2, head layout);
//         2 -> V (from A2, written TRANSPOSED [B,H,64,S] as packed ushort4).
// MODE 2: relu -> bf16 row-major [M,N]    (FFN first GEMM, o0)
// ---------------------------------------------------------------------------
template <int MODE>
__global__ __launch_bounds__(256)
void gemm_kernel(const unsigned short* __restrict__ A,
                 const unsigned short* __restrict__ A2,
                 const unsigned short* __restrict__ Wt,
                 const float* __restrict__ b0,
                 const float* __restrict__ b1,
                 const float* __restrict__ b2,
                 unsigned short* __restrict__ o0,
                 unsigned short* __restrict__ o1,
                 unsigned short* __restrict__ o2,
                 int M, int N, int K)
{
    __shared__ unsigned short As[128 * 32];
    __shared__ unsigned short Bs[128 * 32];
    const int tid  = threadIdx.x;
    const int lane = tid & 63;
    const int wv   = tid >> 6;
    const int quad = lane >> 4;
    const int l16  = lane & 15;
    const int m0 = blockIdx.y * 128;
    const int n0 = blockIdx.x * 128;
    const int wm = (wv >> 1) << 6;
    const int wn = (wv & 1) << 6;
    const int sect = (MODE == 1) ? (n0 >> 10) : 0;
    const unsigned short* Asel = (MODE == 1 && sect != 0) ? A2 : A;

    const int srow0 = wv * 32 + (lane >> 2);
    const int srow1 = srow0 + 16;
    const int scol8 = (lane & 3) * 8;
    unsigned short* asw0 = &As[(wv * 2 + 0) * 512];
    unsigned short* asw1 = &As[(wv * 2 + 1) * 512];
    unsigned short* bsw0 = &Bs[(wv * 2 + 0) * 512];
    unsigned short* bsw1 = &Bs[(wv * 2 + 1) * 512];
    const unsigned short* Ag0 = Asel + (size_t)(m0 + srow0) * K + scol8;
    const unsigned short* Ag1 = Asel + (size_t)(m0 + srow1) * K + scol8;
    const unsigned short* Bg0 = Wt   + (size_t)(n0 + srow0) * K + scol8;
    const unsigned short* Bg1 = Wt   + (size_t)(n0 + srow1) * K + scol8;

    f32x4 acc[4][4];
#pragma unroll
    for (int i = 0; i < 4; i++)
#pragma unroll
        for (int j = 0; j < 4; j++) acc[i][j] = f32x4{0.f, 0.f, 0.f, 0.f};

    for (int k0 = 0; k0 < K; k0 += 32) {
        GLDS(Ag0 + k0, asw0);
        GLDS(Ag1 + k0, asw1);
        GLDS(Bg0 + k0, bsw0);
        GLDS(Bg1 + k0, bsw1);
        __syncthreads();
        short8 af[4], bfr[4];
#pragma unroll
        for (int i = 0; i < 4; i++)
            af[i] = *(const short8*)(&As[(wm + i * 16 + l16) * 32 + quad * 8]);
#pragma unroll
        for (int i = 0; i < 4; i++)
            bfr[i] = *(const short8*)(&Bs[(wn + i * 16 + l16) * 32 + quad * 8]);
#pragma unroll
        for (int mi = 0; mi < 4; mi++)
#pragma unroll
            for (int ni = 0; ni < 4; ni++)
                acc[mi][ni] = __builtin_amdgcn_mfma_f32_16x16x32_bf16(
                    af[mi], bfr[ni], acc[mi][ni], 0, 0, 0);
        __syncthreads();
    }

    if (MODE == 1) {
        const float* bias = (sect == 0) ? b0 : ((sect == 1) ? b1 : b2);
        if (sect == 2) {
            // V: write transposed [B,H,64,S], 4 consecutive s packed per store
#pragma unroll
            for (int mi = 0; mi < 4; mi++)
#pragma unroll
                for (int ni = 0; ni < 4; ni++) {
                    const int cc = (n0 + wn + ni * 16 + l16) & 1023;
                    const int h = cc >> 6, d = cc & 63;
                    const float bv = bias[cc];
                    const int rowg = m0 + wm + mi * 16 + quad * 4;
                    const int b = rowg >> 11, s = rowg & 2047;
                    ushort4 o4;
                    o4.x = f2bf(acc[mi][ni][0] + bv);
                    o4.y = f2bf(acc[mi][ni][1] + bv);
                    o4.z = f2bf(acc[mi][ni][2] + bv);
                    o4.w = f2bf(acc[mi][ni][3] + bv);
                    *(ushort4*)&o2[((size_t)(b * 16 + h) * 64 + d) * SEQ + s] = o4;
                }
        } else {
            unsigned short* dst = (sect == 0) ? o0 : o1;
            const float scl = (sect == 0) ? QSCALE : 1.0f;
#pragma unroll
            for (int mi = 0; mi < 4; mi++)
#pragma unroll
                for (int ni = 0; ni < 4; ni++) {
                    const int cc = (n0 + wn + ni * 16 + l16) & 1023;
                    const int h = cc >> 6, d = cc & 63;
                    const float bv = bias[cc];
#pragma unroll
                    for (int r = 0; r < 4; r++) {
                        const int rowg = m0 + wm + mi * 16 + quad * 4 + r;
                        const int b = rowg >> 11, s = rowg & 2047;
                        float v = (acc[mi][ni][r] + bv) * scl;
                        dst[((size_t)(b * 16 + h) * SEQ + s) * 64 + d] = f2bf(v);
                    }
                }
        }
    } else {
#pragma unroll
        for (int mi = 0; mi < 4; mi++)
#pragma unroll
            for (int ni = 0; ni < 4; ni++) {
                const int colg = n0 + wn + ni * 16 + l16;
                const float bv = b0[colg];
#pragma unroll
                for (int r = 0; r < 4; r++) {
                    const int rowg = m0 + wm + mi * 16 + quad * 4 + r;
                    float v = acc[mi][ni][r] + bv;
                    o0[(size_t)rowg * N + colg] = f2bf(fmaxf(v, 0.f));
                }
            }
    }
}

// ---------------------------------------------------------------------------
// Split-K 128x128 GEMM for FFN2 (M=4096, N=1024, K=4096):
// grid (N/128, M/128, 2) = 512 blocks = 2/CU so barrier drains overlap,
// but with 16 MFMA per barrier (m97 density) instead of gemm64's 8.
// outf ALREADY HOLDS THE RESIDUAL (x2 aliases out), so both splits just
// hardware-atomicAdd their partial (+bias once, on kz==0). All contributions
// are additive -> no write-ordering hazard.
// ---------------------------------------------------------------------------
__global__ __launch_bounds__(256)
void gemm_sk_kernel(const unsigned short* __restrict__ A,
                    const unsigned short* __restrict__ Wt,
                    const float* __restrict__ b0,
                    float* __restrict__ outf,
                    int M, int N, int K, int Kh)
{
    __shared__ unsigned short As[128 * 32];
    __shared__ unsigned short Bs[128 * 32];
    const int tid  = threadIdx.x;
    const int lane = tid & 63;
    const int wv   = tid >> 6;
    const int quad = lane >> 4;
    const int l16  = lane & 15;
    const int m0 = blockIdx.y * 128;
    const int n0 = blockIdx.x * 128;
    const int kz = blockIdx.z;
    const int kbase = kz * Kh;
    const int wm = (wv >> 1) << 6;
    const int wn = (wv & 1) << 6;

    const int srow0 = wv * 32 + (lane >> 2);
    const int srow1 = srow0 + 16;
    const int scol8 = (lane & 3) * 8;
    unsigned short* asw0 = &As[(wv * 2 + 0) * 512];
    unsigned short* asw1 = &As[(wv * 2 + 1) * 512];
    unsigned short* bsw0 = &Bs[(wv * 2 + 0) * 512];
    unsigned short* bsw1 = &Bs[(wv * 2 + 1) * 512];
    const unsigned short* Ag0 = A  + (size_t)(m0 + srow0) * K + kbase + scol8;
    const unsigned short* Ag1 = A  + (size_t)(m0 + srow1) * K + kbase + scol8;
    const unsigned short* Bg0 = Wt + (size_t)(n0 + srow0) * K + kbase + scol8;
    const unsigned short* Bg1 = Wt + (size_t)(n0 + srow1) * K + kbase + scol8;

    f32x4 acc[4][4];
#pragma unroll
    for (int i = 0; i < 4; i++)
#pragma unroll
        for (int j = 0; j < 4; j++) acc[i][j] = f32x4{0.f, 0.f, 0.f, 0.f};

    for (int k0 = 0; k0 < Kh; k0 += 32) {
        GLDS(Ag0 + k0, asw0);
        GLDS(Ag1 + k0, asw1);
        GLDS(Bg0 + k0, bsw0);
        GLDS(Bg1 + k0, bsw1);
        __syncthreads();
        short8 af[4], bfr[4];
#pragma unroll
        for (int i = 0; i < 4; i++)
            af[i] = *(const short8*)(&As[(wm + i * 16 + l16) * 32 + quad * 8]);
#pragma unroll
        for (int i = 0; i < 4; i++)
            bfr[i] = *(const short8*)(&Bs[(wn + i * 16 + l16) * 32 + quad * 8]);
#pragma unroll
        for (int mi = 0; mi < 4; mi++)
#pragma unroll
            for (int ni = 0; ni < 4; ni++)
                acc[mi][ni] = __builtin_amdgcn_mfma_f32_16x16x32_bf16(
                    af[mi], bfr[ni], acc[mi][ni], 0, 0, 0);
        __syncthreads();
    }

    // epilogue: hardware f32 atomic-add into out (which already holds residual)
#pragma unroll
    for (int mi = 0; mi < 4; mi++)
#pragma unroll
        for (int ni = 0; ni < 4; ni++) {
            const int colg = n0 + wn + ni * 16 + l16;
            const float bv = (kz == 0) ? b0[colg] : 0.f;
#pragma unroll
            for (int r = 0; r < 4; r++) {
                const int rowg = m0 + wm + mi * 16 + quad * 4 + r;
                unsafeAtomicAdd(&outf[(size_t)rowg * N + colg],
                                acc[mi][ni][r] + bv);
            }
        }
}

// ---------------------------------------------------------------------------
// 64x128-tile GEMM (+res fp32) for N=1024 output projections:
// grid (8, 64) = 512 blocks = 2 blocks/CU so barrier drains overlap.
// ---------------------------------------------------------------------------
__global__ __launch_bounds__(256)
void gemm64_kernel(const unsigned short* __restrict__ A,
                   const unsigned short* __restrict__ Wt,
                   const float* __restrict__ b0,
                   const float* __restrict__ res,
                   float* __restrict__ outf,
                   int M, int N, int K)
{
    __shared__ unsigned short As[64 * 32];
    __shared__ unsigned short Bs[128 * 32];
    const int tid  = threadIdx.x;
    const int lane = tid & 63;
    const int wv   = tid >> 6;
    const int quad = lane >> 4;
    const int l16  = lane & 15;
    const int m0 = blockIdx.y * 64;
    const int n0 = blockIdx.x * 128;
    const int wm = (wv >> 1) << 5;
    const int wn = (wv & 1) << 6;

    const int arow  = wv * 16 + (lane >> 2);
    const int brow0 = wv * 32 + (lane >> 2);
    const int brow1 = brow0 + 16;
    const int scol8 = (lane & 3) * 8;
    unsigned short* asw  = &As[wv * 512];
    unsigned short* bsw0 = &Bs[(wv * 2 + 0) * 512];
    unsigned short* bsw1 = &Bs[(wv * 2 + 1) * 512];
    const unsigned short* Ag  = A  + (size_t)(m0 + arow)  * K + scol8;
    const unsigned short* Bg0 = Wt + (size_t)(n0 + brow0) * K + scol8;
    const unsigned short* Bg1 = Wt + (size_t)(n0 + brow1) * K + scol8;

    f32x4 acc[2][4];
#pragma unroll
    for (int i = 0; i < 2; i++)
#pragma unroll
        for (int j = 0; j < 4; j++) acc[i][j] = f32x4{0.f, 0.f, 0.f, 0.f};

    for (int k0 = 0; k0 < K; k0 += 32) {
        GLDS(Ag + k0, asw);
        GLDS(Bg0 + k0, bsw0);
        GLDS(Bg1 + k0, bsw1);
        __syncthreads();
        short8 af[2], bfr[4];
#pragma unroll
        for (int i = 0; i < 2; i++)
            af[i] = *(const short8*)(&As[(wm + i * 16 + l16) * 32 + quad * 8]);
#pragma unroll
        for (int i = 0; i < 4; i++)
            bfr[i] = *(const short8*)(&Bs[(wn + i * 16 + l16) * 32 + quad * 8]);
#pragma unroll
        for (int mi = 0; mi < 2; mi++)
#pragma unroll
            for (int ni = 0; ni < 4; ni++)
                acc[mi][ni] = __builtin_amdgcn_mfma_f32_16x16x32_bf16(
                    af[mi], bfr[ni], acc[mi][ni], 0, 0, 0);
        __syncthreads();
    }

#pragma unroll
    for (int mi = 0; mi < 2; mi++)
#pragma unroll
        for (int ni = 0; ni < 4; ni++) {
            const int colg = n0 + wn + ni * 16 + l16;
            const float bv = b0[colg];
#pragma unroll
            for (int r = 0; r < 4; r++) {
                const int rowg = m0 + wm + mi * 16 + quad * 4 + r;
                float v = acc[mi][ni][r] + bv;
                outf[(size_t)rowg * N + colg] = v + res[(size_t)rowg * N + colg];
            }
        }
}

// ---------------------------------------------------------------------------
// Flash attention v4: 128 queries/block (32/wave). Q (pre-scaled), K:
// [B,H,S,64]; VT: [B,H,64,S]; O: [B,S,1024] bf16.
// Fixed-shift base-2 softmax; register prefetch of next K/V tile; Ps
// XOR-swizzled. Causal: blockIdx remapped so co-resident block pairs have
// constant total work (kills the straggler imbalance).
// ---------------------------------------------------------------------------
template <bool CAUSAL>
__global__ __launch_bounds__(256, 2)
void attn4_kernel(const unsigned short* __restrict__ Q,
                  const unsigned short* __restrict__ K,
                  const unsigned short* __restrict__ VT,
                  unsigned short* __restrict__ O)
{
    __shared__ unsigned short Ks[128 * 72];
    __shared__ unsigned short Vt[64 * 136];
    __shared__ unsigned short Ps[4][32 * 136];
    __shared__ float sumS[4][32];
    const int tid  = threadIdx.x;
    const int lane = tid & 63;
    const int wave = tid >> 6;
    const int quad = lane >> 4;
    const int l16  = lane & 15;
    const int bh = blockIdx.y;
    // causal: pair heavy with light so each CU's two blocks sum to 17 tiles
    const int qb = (CAUSAL && (bh & 16)) ? (15 - (int)blockIdx.x) : (int)blockIdx.x;
    const int q0 = qb * 128;
    const size_t baseK = (size_t)bh * SEQ * 64;
    const size_t baseV = (size_t)bh * 64 * SEQ;

    short8 aq[2][2];
#pragma unroll
    for (int qs = 0; qs < 2; qs++) {
        const unsigned short* qp =
            Q + baseK + (size_t)(q0 + wave * 32 + qs * 16 + l16) * 64 + quad * 8;
        aq[qs][0] = *(const short8*)(qp);
        aq[qs][1] = *(const short8*)(qp + 32);
    }
    f32x4 acc[4][2];   // [mi(d)][qs]: O^T row d=mi*16+quad*4+r, col q=l16
#pragma unroll
    for (int i = 0; i < 4; i++)
#pragma unroll
        for (int j = 0; j < 2; j++) acc[i][j] = f32x4{0.f, 0.f, 0.f, 0.f};
    float lsum[2][4] = {{0.f, 0.f, 0.f, 0.f}, {0.f, 0.f, 0.f, 0.f}};

    const int nkb = CAUSAL ? (qb + 1) : (SEQ / 128);
    const int krow = tid >> 1;
    const int kc   = (tid & 1) * 32;
    const int vrow = tid >> 2;
    const int vc   = (tid & 3) * 32;
    const unsigned short* kg = K  + baseK + (size_t)krow * 64 + kc;
    const unsigned short* vg = VT + baseV + (size_t)vrow * SEQ + vc;

    short8 kr0 = *(const short8*)(kg),      kr1 = *(const short8*)(kg + 8);
    short8 kr2 = *(const short8*)(kg + 16), kr3 = *(const short8*)(kg + 24);
    short8 vr0 = *(const short8*)(vg),      vr1 = *(const short8*)(vg + 8);
    short8 vr2 = *(const short8*)(vg + 16), vr3 = *(const short8*)(vg + 24);

    for (int kb = 0; kb < nkb; kb++) {
        __syncthreads();
        *(short8*)&Ks[krow * 72 + kc]      = kr0;
        *(short8*)&Ks[krow * 72 + kc + 8]  = kr1;
        *(short8*)&Ks[krow * 72 + kc + 16] = kr2;
        *(short8*)&Ks[krow * 72 + kc + 24] = kr3;
        *(short8*)&Vt[vrow * 136 + vc]      = vr0;
        *(short8*)&Vt[vrow * 136 + vc + 8]  = vr1;
        *(short8*)&Vt[vrow * 136 + vc + 16] = vr2;
        *(short8*)&Vt[vrow * 136 + vc + 24] = vr3;
        if (kb + 1 < nkb) {
            const unsigned short* kg2 = kg + (size_t)(kb + 1) * 128 * 64;
            const unsigned short* vg2 = vg + (size_t)(kb + 1) * 128;
            kr0 = *(const short8*)(kg2);      kr1 = *(const short8*)(kg2 + 8);
            kr2 = *(const short8*)(kg2 + 16); kr3 = *(const short8*)(kg2 + 24);
            vr0 = *(const short8*)(vg2);      vr1 = *(const short8*)(vg2 + 8);
            vr2 = *(const short8*)(vg2 + 16); vr3 = *(const short8*)(vg2 + 24);
        }
        __syncthreads();

        const bool maskTile = CAUSAL && (kb == nkb - 1);
#pragma unroll
        for (int qs = 0; qs < 2; qs++) {
            f32x4 scf[8];
#pragma unroll
            for (int nt = 0; nt < 8; nt++) {
                f32x4 z = f32x4{0.f, 0.f, 0.f, 0.f};
#pragma unroll
                for (int c = 0; c < 2; c++) {
                    short8 bk = *(const short8*)(&Ks[(nt * 16 + l16) * 72 + c * 32 + quad * 8]);
                    z = __builtin_amdgcn_mfma_f32_16x16x32_bf16(aq[qs][c], bk, z, 0, 0, 0);
                }
                scf[nt] = z;
            }
            if (maskTile) {
                const int qg = q0 + wave * 32 + qs * 16 + quad * 4;
                const int k0 = kb * 128;
#pragma unroll
                for (int nt = 0; nt < 8; nt++) {
                    const int kg_ = k0 + nt * 16 + l16;
#pragma unroll
                    for (int r = 0; r < 4; r++)
                        if (kg_ > qg + r) scf[nt][r] = -1e9f;
                }
            }
#pragma unroll
            for (int nt = 0; nt < 8; nt++)
#pragma unroll
                for (int r = 0; r < 4; r++) {
                    float pv = EXP2(scf[nt][r] - PSHIFT);
                    lsum[qs][r] += pv;
                    Ps[wave][(qs * 16 + quad * 4 + r) * 136 +
                             ((nt * 16 + l16) ^ (quad * 8))] = f2bf(pv);
                }
        }
        // O^T += V^T @ P^T, both operands contiguous b128; Vt reads shared
        const int pswz = 8 * (quad ^ ((l16 >> 2) & 3));
#pragma unroll
        for (int c = 0; c < 4; c++) {
            short8 av[4];
#pragma unroll
            for (int mi = 0; mi < 4; mi++)
                av[mi] = *(const short8*)(&Vt[(mi * 16 + l16) * 136 + c * 32 + quad * 8]);
#pragma unroll
            for (int qs = 0; qs < 2; qs++) {
                short8 bp = *(const short8*)(&Ps[wave][(qs * 16 + l16) * 136 + c * 32 + pswz]);
#pragma unroll
                for (int mi = 0; mi < 4; mi++)
                    acc[mi][qs] = __builtin_amdgcn_mfma_f32_16x16x32_bf16(av[mi], bp, acc[mi][qs], 0, 0, 0);
            }
        }
    }
#pragma unroll
    for (int qs = 0; qs < 2; qs++)
#pragma unroll
        for (int r = 0; r < 4; r++) {
#pragma unroll
            for (int off = 1; off < 16; off <<= 1)
                lsum[qs][r] += __shfl_xor(lsum[qs][r], off, 64);
        }
    if (l16 == 0) {
#pragma unroll
        for (int qs = 0; qs < 2; qs++)
#pragma unroll
            for (int r = 0; r < 4; r++)
                sumS[wave][qs * 16 + quad * 4 + r] = lsum[qs][r];
    }
    __syncthreads();
    const int b = bh >> 4, h = bh & 15;
#pragma unroll
    for (int qs = 0; qs < 2; qs++) {
        const float rcpL = 1.f / sumS[wave][qs * 16 + l16];
        const int qg = q0 + wave * 32 + qs * 16 + l16;
#pragma unroll
        for (int mi = 0; mi < 4; mi++) {
            ushort4 o4;
            o4.x = f2bf(acc[mi][qs][0] * rcpL);
            o4.y = f2bf(acc[mi][qs][1] * rcpL);
            o4.z = f2bf(acc[mi][qs][2] * rcpL);
            o4.w = f2bf(acc[mi][qs][3] * rcpL);
            *(ushort4*)&O[(size_t)(b * SEQ + qg) * 1024 + h * 64 + mi * 16 + quad * 4] = o4;
        }
    }
}

// ---------------------------------------------------------------------------
extern "C" void kernel_launch(void* const* d_in, const int* in_sizes, int n_in,
                              void* d_out, int out_size, void* d_ws, size_t ws_size,
                              hipStream_t stream)
{
    (void)in_sizes; (void)n_in; (void)out_size; (void)ws_size;
    const int B = 2, S = SEQ, D = 1024, DFF = 4096;
    const int M = B * S;  // 4096

    const float* x     = (const float*)d_in[0];
    const float* enc   = (const float*)d_in[1];
    const float* sa_wq = (const float*)d_in[4],  *sa_bq = (const float*)d_in[5];
    const float* sa_wk = (const float*)d_in[6],  *sa_bk = (const float*)d_in[7];
    const float* sa_wv = (const float*)d_in[8],  *sa_bv = (const float*)d_in[9];
    const float* sa_wo = (const float*)d_in[10], *sa_bo = (const float*)d_in[11];
    const float* ca_wq = (const float*)d_in[12], *ca_bq = (const float*)d_in[13];
    const float* ca_wk = (const float*)d_in[14], *ca_bk = (const float*)d_in[15];
    const float* ca_wv = (const float*)d_in[16], *ca_bv = (const float*)d_in[17];
    const float* ca_wo = (const float*)d_in[18], *ca_bo = (const float*)d_in[19];
    const float* ff_w1 = (const float*)d_in[20], *ff_b1 = (const float*)d_in[21];
    const float* ff_w2 = (const float*)d_in[22], *ff_b2 = (const float*)d_in[23];
    const float* n1_g  = (const float*)d_in[24], *n1_b = (const float*)d_in[25];
    const float* n2_g  = (const float*)d_in[26], *n2_b = (const float*)d_in[27];
    const float* n3_g  = (const float*)d_in[28], *n3_b = (const float*)d_in[29];
    float* out = (float*)d_out;

    char* p = (char*)d_ws;
    auto carve = [&](size_t bytes) -> char* {
        char* r = p;
        p += (bytes + 255) & ~(size_t)255;
        return r;
    };
    unsigned short* wt8     = (unsigned short*)carve((size_t)8 * D * D * 2);
    unsigned short* wt_sqkv = wt8;                       // saq, sak, sav contiguous
    unsigned short* wt_sao  = wt8 + (size_t)3 * D * D;
    unsigned short* wt_cqkv = wt8 + (size_t)4 * D * D;   // caq, cak, cav contiguous
    unsigned short* wt_cao  = wt8 + (size_t)7 * D * D;
    unsigned short* wt_ff1  = (unsigned short*)carve((size_t)D * DFF * 2);
    unsigned short* wt_ff2  = (unsigned short*)carve((size_t)DFF * D * 2);
    unsigned short* encb    = (unsigned short*)carve((size_t)M * D * 2);
    unsigned short* hb      = (unsigned short*)carve((size_t)M * D * 2);
    unsigned short* qbuf    = (unsigned short*)carve((size_t)M * D * 2);
    unsigned short* kbuf    = (unsigned short*)carve((size_t)M * D * 2);
    unsigned short* vtbuf   = (unsigned short*)carve((size_t)M * D * 2);
    unsigned short* ffh     = (unsigned short*)carve((size_t)M * DFF * 2);
    float* x1 = (float*)carve((size_t)M * D * 4);
    unsigned short* abuf = hb;   // lifetimes disjoint
    float* x2 = out;             // block-2 residual in d_out; block-3 in-place

    dim3 blk(256);
    wtrans8_kernel<<<dim3(32, 32, 8), blk, 0, stream>>>(
        sa_wq, sa_wk, sa_wv, sa_wo, ca_wq, ca_wk, ca_wv, ca_wo, wt8);
    wtrans_kernel<<<dim3(DFF / 32, D / 32), blk, 0, stream>>>(ff_w1, wt_ff1, D, DFF);
    wtrans_kernel<<<dim3(D / 32, DFF / 32), blk, 0, stream>>>(ff_w2, wt_ff2, DFF, D);
    cvt_kernel<<<dim3(M * D / 1024), blk, 0, stream>>>(enc, encb, M * D);

    // ---- block 1: self-attention ----
    ln_kernel<<<dim3(M), blk, 0, stream>>>(x, n1_g, n1_b, hb);
    gemm_kernel<1><<<dim3(3 * D / 128, M / 128), blk, 0, stream>>>(
        hb, hb, wt_sqkv, sa_bq, sa_bk, sa_bv, qbuf, kbuf, vtbuf, M, 3 * D, D);
    attn4_kernel<true><<<dim3(S / 128, B * 16), blk, 0, stream>>>(qbuf, kbuf, vtbuf, abuf);
    gemm64_kernel<<<dim3(D / 128, M / 64), blk, 0, stream>>>(
        abuf, wt_sao, sa_bo, x, x1, M, D, D);

    // ---- block 2: cross-attention (Q from hb, K/V from encoder) ----
    ln_kernel<<<dim3(M), blk, 0, stream>>>(x1, n2_g, n2_b, hb);
    gemm_kernel<1><<<dim3(3 * D / 128, M / 128), blk, 0, stream>>>(
        hb, encb, wt_cqkv, ca_bq, ca_bk, ca_bv, qbuf, kbuf, vtbuf, M, 3 * D, D);
    attn4_kernel<false><<<dim3(S / 128, B * 16), blk, 0, stream>>>(qbuf, kbuf, vtbuf, abuf);
    gemm64_kernel<<<dim3(D / 128, M / 64), blk, 0, stream>>>(
        abuf, wt_cao, ca_bo, x1, x2, M, D, D);

    // ---- block 3: feed-forward ----
    ln_kernel<<<dim3(M), blk, 0, stream>>>(x2, n3_g, n3_b, hb);
    gemm_kernel<2><<<dim3(DFF / 128, M / 128), blk, 0, stream>>>(
        hb, hb, wt_ff1, ff_b1, nullptr, nullptr, ffh, nullptr, nullptr, M, DFF, D);
    // FFN2: split-K=2, 128x128 tile, atomic accumulate into out (holds x2)
    gemm_sk_kernel<<<dim3(D / 128, M / 128, 2), blk, 0, stream>>>(
        ffh, wt_ff2, ff_b2, out, M, D, DFF, DFF / 2);
}

// Round 2
// 600.443 us; speedup vs baseline: 1.0086x; 1.0086x over previous
//
#include <hip/hip_runtime.h>

typedef short short8 __attribute__((ext_vector_type(8)));
typedef float f32x4 __attribute__((ext_vector_type(4)));

#define SEQ 2048
#define QSCALE 0.18033688011112042f   // 0.125 * log2(e): softmax done in base 2
#define PSHIFT 20.0f                  // fixed softmax shift (cancels in O = acc/l)
#define EXP2(x) __builtin_amdgcn_exp2f(x)

// async global->LDS, 16B per lane; lds base must be wave-uniform
#define GLDS(g, l) __builtin_amdgcn_global_load_lds( \
    (const __attribute__((address_space(1))) unsigned int*)(g), \
    (__attribute__((address_space(3))) unsigned int*)(l), 16, 0, 0)

__device__ __forceinline__ unsigned short f2bf(float f) {
    unsigned int u = __builtin_bit_cast(unsigned int, f);
    unsigned int r = (u + 0x7fffu + ((u >> 16) & 1u)) >> 16;
    return (unsigned short)r;
}

// ---------------------------------------------------------------------------
// Batched weight transpose + fp32->bf16: 8 D x D weights in one launch.
// ---------------------------------------------------------------------------
__global__ __launch_bounds__(256)
void wtrans8_kernel(const float* w0, const float* w1, const float* w2, const float* w3,
                    const float* w4, const float* w5, const float* w6, const float* w7,
                    unsigned short* __restrict__ outbase)
{
    const float* Ws[8] = {w0, w1, w2, w3, w4, w5, w6, w7};
    const float* __restrict__ W = Ws[blockIdx.z];
    unsigned short* __restrict__ Wt = outbase + (size_t)blockIdx.z * 1024 * 1024;
    __shared__ float t[32][33];
    const int tx = threadIdx.x & 31;
    const int ty = threadIdx.x >> 5;
    const int nb = blockIdx.x * 32;
    const int kb = blockIdx.y * 32;
#pragma unroll
    for (int i = 0; i < 4; i++)
        t[ty + i * 8][tx] = W[(size_t)(kb + ty + i * 8) * 1024 + nb + tx];
    __syncthreads();
#pragma unroll
    for (int i = 0; i < 4; i++)
        Wt[(size_t)(nb + ty + i * 8) * 1024 + kb + tx] = f2bf(t[tx][ty + i * 8]);
}

// single weight transpose (for the two FFN shapes)
__global__ __launch_bounds__(256)
void wtrans_kernel(const float* __restrict__ W, unsigned short* __restrict__ Wt,
                   int Kd, int Nd)
{
    __shared__ float t[32][33];
    const int tx = threadIdx.x & 31;
    const int ty = threadIdx.x >> 5;
    const int nb = blockIdx.x * 32;
    const int kb = blockIdx.y * 32;
#pragma unroll
    for (int i = 0; i < 4; i++)
        t[ty + i * 8][tx] = W[(size_t)(kb + ty + i * 8) * Nd + nb + tx];
    __syncthreads();
#pragma unroll
    for (int i = 0; i < 4; i++)
        Wt[(size_t)(nb + ty + i * 8) * Kd + kb + tx] = f2bf(t[tx][ty + i * 8]);
}

// ---------------------------------------------------------------------------
// Elementwise fp32 -> bf16
// ---------------------------------------------------------------------------
__global__ __launch_bounds__(256)
void cvt_kernel(const float* __restrict__ in, unsigned short* __restrict__ out, int n)
{
    int i = (blockIdx.x * 256 + threadIdx.x) * 4;
    if (i < n) {
        float4 v = *(const float4*)(in + i);
        ushort4 o;
        o.x = f2bf(v.x); o.y = f2bf(v.y); o.z = f2bf(v.z); o.w = f2bf(v.w);
        *(ushort4*)(out + i) = o;
    }
}

// ---------------------------------------------------------------------------
// LayerNorm (torch-faithful: ddof=1, eps added to std). fp32 in -> bf16 out.
// ---------------------------------------------------------------------------
__global__ __launch_bounds__(256)
void ln_kernel(const float* __restrict__ x, const float* __restrict__ g,
               const float* __restrict__ bb, unsigned short* __restrict__ out)
{
    const int D = 1024;
    const int row = blockIdx.x;
    const float* xr = x + (size_t)row * D;
    float v[4];
    float s = 0.f, ss = 0.f;
#pragma unroll
    for (int i = 0; i < 4; i++) {
        v[i] = xr[threadIdx.x + i * 256];
        s += v[i];
        ss += v[i] * v[i];
    }
#pragma unroll
    for (int off = 1; off < 64; off <<= 1) {
        s  += __shfl_xor(s,  off, 64);
        ss += __shfl_xor(ss, off, 64);
    }
    __shared__ float red[8];
    const int wave = threadIdx.x >> 6;
    if ((threadIdx.x & 63) == 0) { red[wave] = s; red[4 + wave] = ss; }
    __syncthreads();
    s  = red[0] + red[1] + red[2] + red[3];
    ss = red[4] + red[5] + red[6] + red[7];
    float mean = s / D;
    float var  = fmaxf((ss - s * mean) / (D - 1), 0.f);
    float inv  = 1.f / (sqrtf(var) + 1e-6f);
#pragma unroll
    for (int i = 0; i < 4; i++) {
        int c = threadIdx.x + i * 256;
        out[(size_t)row * D + c] = f2bf(g[c] * (v[i] - mean) * inv + bb[c]);
    }
}

// ---------------------------------------------------------------------------
// Tiled MFMA GEMM (m97 structure): C[M,N] = A[M,K] @ Wt[N,K]^T + bias
// 128x128 tile, BK=32, unpadded LDS, global_load_lds 16B async staging.
// MODE 1: projection GEMM. Section = n0>>10: 0 -> Q (from A, scaled QSCALE,
//         head layout [B,H,S,64]); 1 -> K (from A2, head layout);
//         2 -> V (from A2, written TRANSPOSED [B,H,64,S] as packed ushort4).
// MODE 2: relu -> bf16 row-major [M,N]    (FFN first GEMM, o0)
// ---------------------------------------------------------------------------
template <int MODE>
__global__ __launch_bounds__(256)
void gemm_kernel(const unsigned short* __restrict__ A,
                 const unsigned short* __restrict__ A2,
                 const unsigned short* __restrict__ Wt,
                 const float* __restrict__ b0,
                 const float* __restrict__ b1,
                 const float* __restrict__ b2,
                 unsigned short* __restrict__ o0,
                 unsigned short* __restrict__ o1,
                 unsigned short* __restrict__ o2,
                 int M, int N, int K)
{
    __shared__ unsigned short As[128 * 32];
    __shared__ unsigned short Bs[128 * 32];
    const int tid  = threadIdx.x;
    const int lane = tid & 63;
    const int wv   = tid >> 6;
    const int quad = lane >> 4;
    const int l16  = lane & 15;
    const int m0 = blockIdx.y * 128;
    const int n0 = blockIdx.x * 128;
    const int wm = (wv >> 1) << 6;
    const int wn = (wv & 1) << 6;
    const int sect = (MODE == 1) ? (n0 >> 10) : 0;
    const unsigned short* Asel = (MODE == 1 && sect != 0) ? A2 : A;

    const int srow0 = wv * 32 + (lane >> 2);
    const int srow1 = srow0 + 16;
    const int scol8 = (lane & 3) * 8;
    unsigned short* asw0 = &As[(wv * 2 + 0) * 512];
    unsigned short* asw1 = &As[(wv * 2 + 1) * 512];
    unsigned short* bsw0 = &Bs[(wv * 2 + 0) * 512];
    unsigned short* bsw1 = &Bs[(wv * 2 + 1) * 512];
    const unsigned short* Ag0 = Asel + (size_t)(m0 + srow0) * K + scol8;
    const unsigned short* Ag1 = Asel + (size_t)(m0 + srow1) * K + scol8;
    const unsigned short* Bg0 = Wt   + (size_t)(n0 + srow0) * K + scol8;
    const unsigned short* Bg1 = Wt   + (size_t)(n0 + srow1) * K + scol8;

    f32x4 acc[4][4];
#pragma unroll
    for (int i = 0; i < 4; i++)
#pragma unroll
        for (int j = 0; j < 4; j++) acc[i][j] = f32x4{0.f, 0.f, 0.f, 0.f};

    for (int k0 = 0; k0 < K; k0 += 32) {
        GLDS(Ag0 + k0, asw0);
        GLDS(Ag1 + k0, asw1);
        GLDS(Bg0 + k0, bsw0);
        GLDS(Bg1 + k0, bsw1);
        __syncthreads();
        short8 af[4], bfr[4];
#pragma unroll
        for (int i = 0; i < 4; i++)
            af[i] = *(const short8*)(&As[(wm + i * 16 + l16) * 32 + quad * 8]);
#pragma unroll
        for (int i = 0; i < 4; i++)
            bfr[i] = *(const short8*)(&Bs[(wn + i * 16 + l16) * 32 + quad * 8]);
#pragma unroll
        for (int mi = 0; mi < 4; mi++)
#pragma unroll
            for (int ni = 0; ni < 4; ni++)
                acc[mi][ni] = __builtin_amdgcn_mfma_f32_16x16x32_bf16(
                    af[mi], bfr[ni], acc[mi][ni], 0, 0, 0);
        __syncthreads();
    }

    if (MODE == 1) {
        const float* bias = (sect == 0) ? b0 : ((sect == 1) ? b1 : b2);
        if (sect == 2) {
            // V: write transposed [B,H,64,S], 4 consecutive s packed per store
#pragma unroll
            for (int mi = 0; mi < 4; mi++)
#pragma unroll
                for (int ni = 0; ni < 4; ni++) {
                    const int cc = (n0 + wn + ni * 16 + l16) & 1023;
                    const int h = cc >> 6, d = cc & 63;
                    const float bv = bias[cc];
                    const int rowg = m0 + wm + mi * 16 + quad * 4;
                    const int b = rowg >> 11, s = rowg & 2047;
                    ushort4 o4;
                    o4.x = f2bf(acc[mi][ni][0] + bv);
                    o4.y = f2bf(acc[mi][ni][1] + bv);
                    o4.z = f2bf(acc[mi][ni][2] + bv);
                    o4.w = f2bf(acc[mi][ni][3] + bv);
                    *(ushort4*)&o2[((size_t)(b * 16 + h) * 64 + d) * SEQ + s] = o4;
                }
        } else {
            unsigned short* dst = (sect == 0) ? o0 : o1;
            const float scl = (sect == 0) ? QSCALE : 1.0f;
#pragma unroll
            for (int mi = 0; mi < 4; mi++)
#pragma unroll
                for (int ni = 0; ni < 4; ni++) {
                    const int cc = (n0 + wn + ni * 16 + l16) & 1023;
                    const int h = cc >> 6, d = cc & 63;
                    const float bv = bias[cc];
#pragma unroll
                    for (int r = 0; r < 4; r++) {
                        const int rowg = m0 + wm + mi * 16 + quad * 4 + r;
                        const int b = rowg >> 11, s = rowg & 2047;
                        float v = (acc[mi][ni][r] + bv) * scl;
                        dst[((size_t)(b * 16 + h) * SEQ + s) * 64 + d] = f2bf(v);
                    }
                }
        }
    } else {
#pragma unroll
        for (int mi = 0; mi < 4; mi++)
#pragma unroll
            for (int ni = 0; ni < 4; ni++) {
                const int colg = n0 + wn + ni * 16 + l16;
                const float bv = b0[colg];
#pragma unroll
                for (int r = 0; r < 4; r++) {
                    const int rowg = m0 + wm + mi * 16 + quad * 4 + r;
                    float v = acc[mi][ni][r] + bv;
                    o0[(size_t)rowg * N + colg] = f2bf(fmaxf(v, 0.f));
                }
            }
    }
}

// ---------------------------------------------------------------------------
// Double-buffered 2-phase GEMM for the N=1024 shapes (grid-limited to
// 1 block/CU, so latency must be hidden in-wave, not by co-resident blocks):
// C[M,N] = A[M,K] @ Wt[N,K]^T + bias + res   (fp32 out, fused residual)
// 128x128 tile, BK=64, 4 waves. Per K-step: issue next tile's 8
// global_load_lds, compute current tile (32 MFMA), then ONE
// vmcnt(0)+raw-barrier -- next-tile HBM latency hides under compute.
// LDS reads are XOR-swizzled (T2); since global_load_lds writes linearly,
// the swizzle is applied by permuting the per-lane GLOBAL source address
// (rule #21: linear dest + inverse-swizzled source + swizzled read).
// ---------------------------------------------------------------------------
__global__ __launch_bounds__(256, 1)
void gemm_db_kernel(const unsigned short* __restrict__ A,
                    const unsigned short* __restrict__ Wt,
                    const float* __restrict__ b0,
                    const float* __restrict__ res,
                    float* __restrict__ outf,
                    int M, int N, int K)
{
    __shared__ unsigned short As[2][128 * 64];
    __shared__ unsigned short Bs[2][128 * 64];
    const int tid  = threadIdx.x;
    const int lane = tid & 63;
    const int wv   = tid >> 6;
    const int quad = lane >> 4;
    const int l16  = lane & 15;
    const int m0 = blockIdx.y * 128;
    const int n0 = blockIdx.x * 128;
    const int wm = (wv >> 1) << 6;
    const int wn = (wv & 1) << 6;

    // staging: wave wv owns rows [wv*32, wv*32+32) of each 128x64 tile,
    // as 4 chunks of 8 rows (1KB per GLDS round). Linear LDS dest; the
    // col-unit is XOR'd into the source address so that LDS unit u of row r
    // holds global unit u^(r&7).
    const int rsub = lane >> 3;                    // 0..7 row within chunk
    const int cu8  = ((lane & 7) ^ rsub) * 8;      // swizzled source col (elems)
    const unsigned short* Ag = A  + (size_t)(m0 + wv * 32 + rsub) * K + cu8;
    const unsigned short* Bg = Wt + (size_t)(n0 + wv * 32 + rsub) * K + cu8;

    f32x4 acc[4][4];
#pragma unroll
    for (int i = 0; i < 4; i++)
#pragma unroll
        for (int j = 0; j < 4; j++) acc[i][j] = f32x4{0.f, 0.f, 0.f, 0.f};

    const int NT = K >> 6;

    // prologue: stage tile 0 into buffer 0
#pragma unroll
    for (int r = 0; r < 4; r++) {
        GLDS(Ag + (size_t)(r * 8) * K, &As[0][(wv * 4 + r) * 512]);
        GLDS(Bg + (size_t)(r * 8) * K, &Bs[0][(wv * 4 + r) * 512]);
    }
    asm volatile("s_waitcnt vmcnt(0)" ::: "memory");
    __builtin_amdgcn_s_barrier();

    for (int i = 0; i < NT; i++) {
        const int cur = i & 1;
        if (i + 1 < NT) {
            const int nb = cur ^ 1;
            const int kb = (i + 1) << 6;
#pragma unroll
            for (int r = 0; r < 4; r++) {
                GLDS(Ag + (size_t)(r * 8) * K + kb, &As[nb][(wv * 4 + r) * 512]);
                GLDS(Bg + (size_t)(r * 8) * K + kb, &Bs[nb][(wv * 4 + r) * 512]);
            }
        }
        // compute current buffer: 2 K-slices x 16 MFMA
#pragma unroll
        for (int ks = 0; ks < 2; ks++) {
            short8 af[4], bfr[4];
#pragma unroll
            for (int mi = 0; mi < 4; mi++)
                af[mi] = *(const short8*)(&As[cur][(wm + mi * 16 + l16) * 64 +
                             (((ks * 4 + quad) ^ (l16 & 7)) * 8)]);
#pragma unroll
            for (int ni = 0; ni < 4; ni++)
                bfr[ni] = *(const short8*)(&Bs[cur][(wn + ni * 16 + l16) * 64 +
                             (((ks * 4 + quad) ^ (l16 & 7)) * 8)]);
#pragma unroll
            for (int mi = 0; mi < 4; mi++)
#pragma unroll
                for (int ni = 0; ni < 4; ni++)
                    acc[mi][ni] = __builtin_amdgcn_mfma_f32_16x16x32_bf16(
                        af[mi], bfr[ni], acc[mi][ni], 0, 0, 0);
        }
        // single drain+barrier per K-step: next-tile loads flew during compute
        asm volatile("s_waitcnt vmcnt(0) lgkmcnt(0)" ::: "memory");
        __builtin_amdgcn_s_barrier();
    }

    // epilogue: bias + fused residual, fp32 out
#pragma unroll
    for (int mi = 0; mi < 4; mi++)
#pragma unroll
        for (int ni = 0; ni < 4; ni++) {
            const int colg = n0 + wn + ni * 16 + l16;
            const float bv = b0[colg];
#pragma unroll
            for (int r = 0; r < 4; r++) {
                const int rowg = m0 + wm + mi * 16 + quad * 4 + r;
                outf[(size_t)rowg * N + colg] =
                    acc[mi][ni][r] + bv + res[(size_t)rowg * N + colg];
            }
        }
}

// ---------------------------------------------------------------------------
// Flash attention v4: 128 queries/block (32/wave). Q (pre-scaled), K:
// [B,H,S,64]; VT: [B,H,64,S]; O: [B,S,1024] bf16.
// Fixed-shift base-2 softmax; register prefetch of next K/V tile; Ps
// XOR-swizzled. Causal: blockIdx remapped so co-resident block pairs have
// constant total work (kills the straggler imbalance).
// ---------------------------------------------------------------------------
template <bool CAUSAL>
__global__ __launch_bounds__(256, 2)
void attn4_kernel(const unsigned short* __restrict__ Q,
                  const unsigned short* __restrict__ K,
                  const unsigned short* __restrict__ VT,
                  unsigned short* __restrict__ O)
{
    __shared__ unsigned short Ks[128 * 72];
    __shared__ unsigned short Vt[64 * 136];
    __shared__ unsigned short Ps[4][32 * 136];
    __shared__ float sumS[4][32];
    const int tid  = threadIdx.x;
    const int lane = tid & 63;
    const int wave = tid >> 6;
    const int quad = lane >> 4;
    const int l16  = lane & 15;
    const int bh = blockIdx.y;
    // causal: pair heavy with light so each CU's two blocks sum to 17 tiles
    const int qb = (CAUSAL && (bh & 16)) ? (15 - (int)blockIdx.x) : (int)blockIdx.x;
    const int q0 = qb * 128;
    const size_t baseK = (size_t)bh * SEQ * 64;
    const size_t baseV = (size_t)bh * 64 * SEQ;

    short8 aq[2][2];
#pragma unroll
    for (int qs = 0; qs < 2; qs++) {
        const unsigned short* qp =
            Q + baseK + (size_t)(q0 + wave * 32 + qs * 16 + l16) * 64 + quad * 8;
        aq[qs][0] = *(const short8*)(qp);
        aq[qs][1] = *(const short8*)(qp + 32);
    }
    f32x4 acc[4][2];   // [mi(d)][qs]: O^T row d=mi*16+quad*4+r, col q=l16
#pragma unroll
    for (int i = 0; i < 4; i++)
#pragma unroll
        for (int j = 0; j < 2; j++) acc[i][j] = f32x4{0.f, 0.f, 0.f, 0.f};
    float lsum[2][4] = {{0.f, 0.f, 0.f, 0.f}, {0.f, 0.f, 0.f, 0.f}};

    const int nkb = CAUSAL ? (qb + 1) : (SEQ / 128);
    const int krow = tid >> 1;
    const int kc   = (tid & 1) * 32;
    const int vrow = tid >> 2;
    const int vc   = (tid & 3) * 32;
    const unsigned short* kg = K  + baseK + (size_t)krow * 64 + kc;
    const unsigned short* vg = VT + baseV + (size_t)vrow * SEQ + vc;

    short8 kr0 = *(const short8*)(kg),      kr1 = *(const short8*)(kg + 8);
    short8 kr2 = *(const short8*)(kg + 16), kr3 = *(const short8*)(kg + 24);
    short8 vr0 = *(const short8*)(vg),      vr1 = *(const short8*)(vg + 8);
    short8 vr2 = *(const short8*)(vg + 16), vr3 = *(const short8*)(vg + 24);

    for (int kb = 0; kb < nkb; kb++) {
        __syncthreads();
        *(short8*)&Ks[krow * 72 + kc]      = kr0;
        *(short8*)&Ks[krow * 72 + kc + 8]  = kr1;
        *(short8*)&Ks[krow * 72 + kc + 16] = kr2;
        *(short8*)&Ks[krow * 72 + kc + 24] = kr3;
        *(short8*)&Vt[vrow * 136 + vc]      = vr0;
        *(short8*)&Vt[vrow * 136 + vc + 8]  = vr1;
        *(short8*)&Vt[vrow * 136 + vc + 16] = vr2;
        *(short8*)&Vt[vrow * 136 + vc + 24] = vr3;
        if (kb + 1 < nkb) {
            const unsigned short* kg2 = kg + (size_t)(kb + 1) * 128 * 64;
            const unsigned short* vg2 = vg + (size_t)(kb + 1) * 128;
            kr0 = *(const short8*)(kg2);      kr1 = *(const short8*)(kg2 + 8);
            kr2 = *(const short8*)(kg2 + 16); kr3 = *(const short8*)(kg2 + 24);
            vr0 = *(const short8*)(vg2);      vr1 = *(const short8*)(vg2 + 8);
            vr2 = *(const short8*)(vg2 + 16); vr3 = *(const short8*)(vg2 + 24);
        }
        __syncthreads();

        const bool maskTile = CAUSAL && (kb == nkb - 1);
#pragma unroll
        for (int qs = 0; qs < 2; qs++) {
            f32x4 scf[8];
#pragma unroll
            for (int nt = 0; nt < 8; nt++) {
                f32x4 z = f32x4{0.f, 0.f, 0.f, 0.f};
#pragma unroll
                for (int c = 0; c < 2; c++) {
                    short8 bk = *(const short8*)(&Ks[(nt * 16 + l16) * 72 + c * 32 + quad * 8]);
                    z = __builtin_amdgcn_mfma_f32_16x16x32_bf16(aq[qs][c], bk, z, 0, 0, 0);
                }
                scf[nt] = z;
            }
            if (maskTile) {
                const int qg = q0 + wave * 32 + qs * 16 + quad * 4;
                const int k0 = kb * 128;
#pragma unroll
                for (int nt = 0; nt < 8; nt++) {
                    const int kg_ = k0 + nt * 16 + l16;
#pragma unroll
                    for (int r = 0; r < 4; r++)
                        if (kg_ > qg + r) scf[nt][r] = -1e9f;
                }
            }
#pragma unroll
            for (int nt = 0; nt < 8; nt++)
#pragma unroll
                for (int r = 0; r < 4; r++) {
                    float pv = EXP2(scf[nt][r] - PSHIFT);
                    lsum[qs][r] += pv;
                    Ps[wave][(qs * 16 + quad * 4 + r) * 136 +
                             ((nt * 16 + l16) ^ (quad * 8))] = f2bf(pv);
                }
        }
        // O^T += V^T @ P^T, both operands contiguous b128; Vt reads shared
        const int pswz = 8 * (quad ^ ((l16 >> 2) & 3));
#pragma unroll
        for (int c = 0; c < 4; c++) {
            short8 av[4];
#pragma unroll
            for (int mi = 0; mi < 4; mi++)
                av[mi] = *(const short8*)(&Vt[(mi * 16 + l16) * 136 + c * 32 + quad * 8]);
#pragma unroll
            for (int qs = 0; qs < 2; qs++) {
                short8 bp = *(const short8*)(&Ps[wave][(qs * 16 + l16) * 136 + c * 32 + pswz]);
#pragma unroll
                for (int mi = 0; mi < 4; mi++)
                    acc[mi][qs] = __builtin_amdgcn_mfma_f32_16x16x32_bf16(av[mi], bp, acc[mi][qs], 0, 0, 0);
            }
        }
    }
#pragma unroll
    for (int qs = 0; qs < 2; qs++)
#pragma unroll
        for (int r = 0; r < 4; r++) {
#pragma unroll
            for (int off = 1; off < 16; off <<= 1)
                lsum[qs][r] += __shfl_xor(lsum[qs][r], off, 64);
        }
    if (l16 == 0) {
#pragma unroll
        for (int qs = 0; qs < 2; qs++)
#pragma unroll
            for (int r = 0; r < 4; r++)
                sumS[wave][qs * 16 + quad * 4 + r] = lsum[qs][r];
    }
    __syncthreads();
    const int b = bh >> 4, h = bh & 15;
#pragma unroll
    for (int qs = 0; qs < 2; qs++) {
        const float rcpL = 1.f / sumS[wave][qs * 16 + l16];
        const int qg = q0 + wave * 32 + qs * 16 + l16;
#pragma unroll
        for (int mi = 0; mi < 4; mi++) {
            ushort4 o4;
            o4.x = f2bf(acc[mi][qs][0] * rcpL);
            o4.y = f2bf(acc[mi][qs][1] * rcpL);
            o4.z = f2bf(acc[mi][qs][2] * rcpL);
            o4.w = f2bf(acc[mi][qs][3] * rcpL);
            *(ushort4*)&O[(size_t)(b * SEQ + qg) * 1024 + h * 64 + mi * 16 + quad * 4] = o4;
        }
    }
}

// ---------------------------------------------------------------------------
extern "C" void kernel_launch(void* const* d_in, const int* in_sizes, int n_in,
                              void* d_out, int out_size, void* d_ws, size_t ws_size,
                              hipStream_t stream)
{
    (void)in_sizes; (void)n_in; (void)out_size; (void)ws_size;
    const int B = 2, S = SEQ, D = 1024, DFF = 4096;
    const int M = B * S;  // 4096

    const float* x     = (const float*)d_in[0];
    const float* enc   = (const float*)d_in[1];
    const float* sa_wq = (const float*)d_in[4],  *sa_bq = (const float*)d_in[5];
    const float* sa_wk = (const float*)d_in[6],  *sa_bk = (const float*)d_in[7];
    const float* sa_wv = (const float*)d_in[8],  *sa_bv = (const float*)d_in[9];
    const float* sa_wo = (const float*)d_in[10], *sa_bo = (const float*)d_in[11];
    const float* ca_wq = (const float*)d_in[12], *ca_bq = (const float*)d_in[13];
    const float* ca_wk = (const float*)d_in[14], *ca_bk = (const float*)d_in[15];
    const float* ca_wv = (const float*)d_in[16], *ca_bv = (const float*)d_in[17];
    const float* ca_wo = (const float*)d_in[18], *ca_bo = (const float*)d_in[19];
    const float* ff_w1 = (const float*)d_in[20], *ff_b1 = (const float*)d_in[21];
    const float* ff_w2 = (const float*)d_in[22], *ff_b2 = (const float*)d_in[23];
    const float* n1_g  = (const float*)d_in[24], *n1_b = (const float*)d_in[25];
    const float* n2_g  = (const float*)d_in[26], *n2_b = (const float*)d_in[27];
    const float* n3_g  = (const float*)d_in[28], *n3_b = (const float*)d_in[29];
    float* out = (float*)d_out;

    char* p = (char*)d_ws;
    auto carve = [&](size_t bytes) -> char* {
        char* r = p;
        p += (bytes + 255) & ~(size_t)255;
        return r;
    };
    unsigned short* wt8     = (unsigned short*)carve((size_t)8 * D * D * 2);
    unsigned short* wt_sqkv = wt8;                       // saq, sak, sav contiguous
    unsigned short* wt_sao  = wt8 + (size_t)3 * D * D;
    unsigned short* wt_cqkv = wt8 + (size_t)4 * D * D;   // caq, cak, cav contiguous
    unsigned short* wt_cao  = wt8 + (size_t)7 * D * D;
    unsigned short* wt_ff1  = (unsigned short*)carve((size_t)D * DFF * 2);
    unsigned short* wt_ff2  = (unsigned short*)carve((size_t)DFF * D * 2);
    unsigned short* encb    = (unsigned short*)carve((size_t)M * D * 2);
    unsigned short* hb      = (unsigned short*)carve((size_t)M * D * 2);
    unsigned short* qbuf    = (unsigned short*)carve((size_t)M * D * 2);
    unsigned short* kbuf    = (unsigned short*)carve((size_t)M * D * 2);
    unsigned short* vtbuf   = (unsigned short*)carve((size_t)M * D * 2);
    unsigned short* ffh     = (unsigned short*)carve((size_t)M * DFF * 2);
    float* x1 = (float*)carve((size_t)M * D * 4);
    unsigned short* abuf = hb;   // lifetimes disjoint
    float* x2 = out;             // block-2 residual in d_out; block-3 in-place

    dim3 blk(256);
    wtrans8_kernel<<<dim3(32, 32, 8), blk, 0, stream>>>(
        sa_wq, sa_wk, sa_wv, sa_wo, ca_wq, ca_wk, ca_wv, ca_wo, wt8);
    wtrans_kernel<<<dim3(DFF / 32, D / 32), blk, 0, stream>>>(ff_w1, wt_ff1, D, DFF);
    wtrans_kernel<<<dim3(D / 32, DFF / 32), blk, 0, stream>>>(ff_w2, wt_ff2, DFF, D);
    cvt_kernel<<<dim3(M * D / 1024), blk, 0, stream>>>(enc, encb, M * D);

    // ---- block 1: self-attention ----
    ln_kernel<<<dim3(M), blk, 0, stream>>>(x, n1_g, n1_b, hb);
    gemm_kernel<1><<<dim3(3 * D / 128, M / 128), blk, 0, stream>>>(
        hb, hb, wt_sqkv, sa_bq, sa_bk, sa_bv, qbuf, kbuf, vtbuf, M, 3 * D, D);
    attn4_kernel<true><<<dim3(S / 128, B * 16), blk, 0, stream>>>(qbuf, kbuf, vtbuf, abuf);
    gemm_db_kernel<<<dim3(D / 128, M / 128), blk, 0, stream>>>(
        abuf, wt_sao, sa_bo, x, x1, M, D, D);

    // ---- block 2: cross-attention (Q from hb, K/V from encoder) ----
    ln_kernel<<<dim3(M), blk, 0, stream>>>(x1, n2_g, n2_b, hb);
    gemm_kernel<1><<<dim3(3 * D / 128, M / 128), blk, 0, stream>>>(
        hb, encb, wt_cqkv, ca_bq, ca_bk, ca_bv, qbuf, kbuf, vtbuf, M, 3 * D, D);
    attn4_kernel<false><<<dim3(S / 128, B * 16), blk, 0, stream>>>(qbuf, kbuf, vtbuf, abuf);
    gemm_db_kernel<<<dim3(D / 128, M / 128), blk, 0, stream>>>(
        abuf, wt_cao, ca_bo, x1, x2, M, D, D);

    // ---- block 3: feed-forward ----
    ln_kernel<<<dim3(M), blk, 0, stream>>>(x2, n3_g, n3_b, hb);
    gemm_kernel<2><<<dim3(DFF / 128, M / 128), blk, 0, stream>>>(
        hb, hb, wt_ff1, ff_b1, nullptr, nullptr, ffh, nullptr, nullptr, M, DFF, D);
    gemm_db_kernel<<<dim3(D / 128, M / 128), blk, 0, stream>>>(
        ffh, wt_ff2, ff_b2, x2, out, M, D, DFF);
}

// Round 3
// 594.282 us; speedup vs baseline: 1.0190x; 1.0104x over previous
//
#include <hip/hip_runtime.h>

typedef short short8 __attribute__((ext_vector_type(8)));
typedef float f32x4 __attribute__((ext_vector_type(4)));

#define SEQ 2048
#define QSCALE 0.18033688011112042f   // 0.125 * log2(e): softmax done in base 2
#define PSHIFT 20.0f                  // fixed softmax shift (cancels in O = acc/l)
#define EXP2(x) __builtin_amdgcn_exp2f(x)

// async global->LDS, 16B per lane; lds base must be wave-uniform
#define GLDS(g, l) __builtin_amdgcn_global_load_lds( \
    (const __attribute__((address_space(1))) unsigned int*)(g), \
    (__attribute__((address_space(3))) unsigned int*)(l), 16, 0, 0)

__device__ __forceinline__ unsigned short f2bf(float f) {
    unsigned int u = __builtin_bit_cast(unsigned int, f);
    unsigned int r = (u + 0x7fffu + ((u >> 16) & 1u)) >> 16;
    return (unsigned short)r;
}

// ---------------------------------------------------------------------------
// Batched weight transpose + fp32->bf16: 8 D x D weights in one launch.
// ---------------------------------------------------------------------------
__global__ __launch_bounds__(256)
void wtrans8_kernel(const float* w0, const float* w1, const float* w2, const float* w3,
                    const float* w4, const float* w5, const float* w6, const float* w7,
                    unsigned short* __restrict__ outbase)
{
    const float* Ws[8] = {w0, w1, w2, w3, w4, w5, w6, w7};
    const float* __restrict__ W = Ws[blockIdx.z];
    unsigned short* __restrict__ Wt = outbase + (size_t)blockIdx.z * 1024 * 1024;
    __shared__ float t[32][33];
    const int tx = threadIdx.x & 31;
    const int ty = threadIdx.x >> 5;
    const int nb = blockIdx.x * 32;
    const int kb = blockIdx.y * 32;
#pragma unroll
    for (int i = 0; i < 4; i++)
        t[ty + i * 8][tx] = W[(size_t)(kb + ty + i * 8) * 1024 + nb + tx];
    __syncthreads();
#pragma unroll
    for (int i = 0; i < 4; i++)
        Wt[(size_t)(nb + ty + i * 8) * 1024 + kb + tx] = f2bf(t[tx][ty + i * 8]);
}

// single weight transpose (for the two FFN shapes)
__global__ __launch_bounds__(256)
void wtrans_kernel(const float* __restrict__ W, unsigned short* __restrict__ Wt,
                   int Kd, int Nd)
{
    __shared__ float t[32][33];
    const int tx = threadIdx.x & 31;
    const int ty = threadIdx.x >> 5;
    const int nb = blockIdx.x * 32;
    const int kb = blockIdx.y * 32;
#pragma unroll
    for (int i = 0; i < 4; i++)
        t[ty + i * 8][tx] = W[(size_t)(kb + ty + i * 8) * Nd + nb + tx];
    __syncthreads();
#pragma unroll
    for (int i = 0; i < 4; i++)
        Wt[(size_t)(nb + ty + i * 8) * Kd + kb + tx] = f2bf(t[tx][ty + i * 8]);
}

// ---------------------------------------------------------------------------
// Elementwise fp32 -> bf16
// ---------------------------------------------------------------------------
__global__ __launch_bounds__(256)
void cvt_kernel(const float* __restrict__ in, unsigned short* __restrict__ out, int n)
{
    int i = (blockIdx.x * 256 + threadIdx.x) * 4;
    if (i < n) {
        float4 v = *(const float4*)(in + i);
        ushort4 o;
        o.x = f2bf(v.x); o.y = f2bf(v.y); o.z = f2bf(v.z); o.w = f2bf(v.w);
        *(ushort4*)(out + i) = o;
    }
}

// ---------------------------------------------------------------------------
// LayerNorm (torch-faithful: ddof=1, eps added to std). fp32 in -> bf16 out.
// ---------------------------------------------------------------------------
__global__ __launch_bounds__(256)
void ln_kernel(const float* __restrict__ x, const float* __restrict__ g,
               const float* __restrict__ bb, unsigned short* __restrict__ out)
{
    const int D = 1024;
    const int row = blockIdx.x;
    const float* xr = x + (size_t)row * D;
    float v[4];
    float s = 0.f, ss = 0.f;
#pragma unroll
    for (int i = 0; i < 4; i++) {
        v[i] = xr[threadIdx.x + i * 256];
        s += v[i];
        ss += v[i] * v[i];
    }
#pragma unroll
    for (int off = 1; off < 64; off <<= 1) {
        s  += __shfl_xor(s,  off, 64);
        ss += __shfl_xor(ss, off, 64);
    }
    __shared__ float red[8];
    const int wave = threadIdx.x >> 6;
    if ((threadIdx.x & 63) == 0) { red[wave] = s; red[4 + wave] = ss; }
    __syncthreads();
    s  = red[0] + red[1] + red[2] + red[3];
    ss = red[4] + red[5] + red[6] + red[7];
    float mean = s / D;
    float var  = fmaxf((ss - s * mean) / (D - 1), 0.f);
    float inv  = 1.f / (sqrtf(var) + 1e-6f);
#pragma unroll
    for (int i = 0; i < 4; i++) {
        int c = threadIdx.x + i * 256;
        out[(size_t)row * D + c] = f2bf(g[c] * (v[i] - mean) * inv + bb[c]);
    }
}

// ---------------------------------------------------------------------------
// Tiled MFMA GEMM (m97 structure): C[M,N] = A[M,K] @ Wt[N,K]^T + bias
// 128x128 tile, BK=32, unpadded LDS, global_load_lds 16B async staging.
// MODE 1: projection GEMM. Section = n0>>10: 0 -> Q (from A, scaled QSCALE,
//         head layout [B,H,S,64]); 1 -> K (from A2, head layout);
//         2 -> V (from A2, written TRANSPOSED [B,H,64,S] as packed ushort4).
// MODE 2: relu -> bf16 row-major [M,N]    (FFN first GEMM, o0)
// ---------------------------------------------------------------------------
template <int MODE>
__global__ __launch_bounds__(256)
void gemm_kernel(const unsigned short* __restrict__ A,
                 const unsigned short* __restrict__ A2,
                 const unsigned short* __restrict__ Wt,
                 const float* __restrict__ b0,
                 const float* __restrict__ b1,
                 const float* __restrict__ b2,
                 unsigned short* __restrict__ o0,
                 unsigned short* __restrict__ o1,
                 unsigned short* __restrict__ o2,
                 int M, int N, int K)
{
    __shared__ unsigned short As[128 * 32];
    __shared__ unsigned short Bs[128 * 32];
    const int tid  = threadIdx.x;
    const int lane = tid & 63;
    const int wv   = tid >> 6;
    const int quad = lane >> 4;
    const int l16  = lane & 15;
    const int m0 = blockIdx.y * 128;
    const int n0 = blockIdx.x * 128;
    const int wm = (wv >> 1) << 6;
    const int wn = (wv & 1) << 6;
    const int sect = (MODE == 1) ? (n0 >> 10) : 0;
    const unsigned short* Asel = (MODE == 1 && sect != 0) ? A2 : A;

    const int srow0 = wv * 32 + (lane >> 2);
    const int srow1 = srow0 + 16;
    const int scol8 = (lane & 3) * 8;
    unsigned short* asw0 = &As[(wv * 2 + 0) * 512];
    unsigned short* asw1 = &As[(wv * 2 + 1) * 512];
    unsigned short* bsw0 = &Bs[(wv * 2 + 0) * 512];
    unsigned short* bsw1 = &Bs[(wv * 2 + 1) * 512];
    const unsigned short* Ag0 = Asel + (size_t)(m0 + srow0) * K + scol8;
    const unsigned short* Ag1 = Asel + (size_t)(m0 + srow1) * K + scol8;
    const unsigned short* Bg0 = Wt   + (size_t)(n0 + srow0) * K + scol8;
    const unsigned short* Bg1 = Wt   + (size_t)(n0 + srow1) * K + scol8;

    f32x4 acc[4][4];
#pragma unroll
    for (int i = 0; i < 4; i++)
#pragma unroll
        for (int j = 0; j < 4; j++) acc[i][j] = f32x4{0.f, 0.f, 0.f, 0.f};

    for (int k0 = 0; k0 < K; k0 += 32) {
        GLDS(Ag0 + k0, asw0);
        GLDS(Ag1 + k0, asw1);
        GLDS(Bg0 + k0, bsw0);
        GLDS(Bg1 + k0, bsw1);
        __syncthreads();
        short8 af[4], bfr[4];
#pragma unroll
        for (int i = 0; i < 4; i++)
            af[i] = *(const short8*)(&As[(wm + i * 16 + l16) * 32 + quad * 8]);
#pragma unroll
        for (int i = 0; i < 4; i++)
            bfr[i] = *(const short8*)(&Bs[(wn + i * 16 + l16) * 32 + quad * 8]);
#pragma unroll
        for (int mi = 0; mi < 4; mi++)
#pragma unroll
            for (int ni = 0; ni < 4; ni++)
                acc[mi][ni] = __builtin_amdgcn_mfma_f32_16x16x32_bf16(
                    af[mi], bfr[ni], acc[mi][ni], 0, 0, 0);
        __syncthreads();
    }

    if (MODE == 1) {
        const float* bias = (sect == 0) ? b0 : ((sect == 1) ? b1 : b2);
        if (sect == 2) {
            // V: write transposed [B,H,64,S], 4 consecutive s packed per store
#pragma unroll
            for (int mi = 0; mi < 4; mi++)
#pragma unroll
                for (int ni = 0; ni < 4; ni++) {
                    const int cc = (n0 + wn + ni * 16 + l16) & 1023;
                    const int h = cc >> 6, d = cc & 63;
                    const float bv = bias[cc];
                    const int rowg = m0 + wm + mi * 16 + quad * 4;
                    const int b = rowg >> 11, s = rowg & 2047;
                    ushort4 o4;
                    o4.x = f2bf(acc[mi][ni][0] + bv);
                    o4.y = f2bf(acc[mi][ni][1] + bv);
                    o4.z = f2bf(acc[mi][ni][2] + bv);
                    o4.w = f2bf(acc[mi][ni][3] + bv);
                    *(ushort4*)&o2[((size_t)(b * 16 + h) * 64 + d) * SEQ + s] = o4;
                }
        } else {
            unsigned short* dst = (sect == 0) ? o0 : o1;
            const float scl = (sect == 0) ? QSCALE : 1.0f;
#pragma unroll
            for (int mi = 0; mi < 4; mi++)
#pragma unroll
                for (int ni = 0; ni < 4; ni++) {
                    const int cc = (n0 + wn + ni * 16 + l16) & 1023;
                    const int h = cc >> 6, d = cc & 63;
                    const float bv = bias[cc];
#pragma unroll
                    for (int r = 0; r < 4; r++) {
                        const int rowg = m0 + wm + mi * 16 + quad * 4 + r;
                        const int b = rowg >> 11, s = rowg & 2047;
                        float v = (acc[mi][ni][r] + bv) * scl;
                        dst[((size_t)(b * 16 + h) * SEQ + s) * 64 + d] = f2bf(v);
                    }
                }
        }
    } else {
#pragma unroll
        for (int mi = 0; mi < 4; mi++)
#pragma unroll
            for (int ni = 0; ni < 4; ni++) {
                const int colg = n0 + wn + ni * 16 + l16;
                const float bv = b0[colg];
#pragma unroll
                for (int r = 0; r < 4; r++) {
                    const int rowg = m0 + wm + mi * 16 + quad * 4 + r;
                    float v = acc[mi][ni][r] + bv;
                    o0[(size_t)rowg * N + colg] = f2bf(fmaxf(v, 0.f));
                }
            }
    }
}

// ---------------------------------------------------------------------------
// Deep-pipelined GEMM for the N=1024 shapes (1 block/CU -> in-wave hiding):
// C[M,N] = A[M,K] @ Wt[N,K]^T + bias + res   (fp32 out, fused residual)
// 128x128 tile, BK=64, 4 waves. THREE LDS buffers, prefetch depth 2:
// at iter i, tile i is computed while tiles i+1 and i+2 are in flight
// (64 KB/CU outstanding); counted s_waitcnt vmcnt(16/8) -- never 0 in
// steady state -- so loads cross barriers (T3/T4).
// XCD rectangle-partition swizzle (cm x cn tiles per XCD): blocks land on
// XCD id%8; the cmxcn rectangle minimizes per-XCD unique A/B bytes
// (the default mapping gave each XCD ONE n-stripe => all of A refetched 8x).
// LDS reads XOR-swizzled; global_load_lds writes linearly so the swizzle is
// pre-applied to the per-lane GLOBAL source address (rule #21).
// ---------------------------------------------------------------------------
__global__ __launch_bounds__(256, 1)
void gemm_db_kernel(const unsigned short* __restrict__ A,
                    const unsigned short* __restrict__ Wt,
                    const float* __restrict__ b0,
                    const float* __restrict__ res,
                    float* __restrict__ outf,
                    int M, int N, int K, int cm, int cn)
{
    __shared__ unsigned short As[3][128 * 64];
    __shared__ unsigned short Bs[3][128 * 64];
    const int tid  = threadIdx.x;
    const int lane = tid & 63;
    const int wv   = tid >> 6;
    const int quad = lane >> 4;
    const int l16  = lane & 15;
    // XCD partition: id%8 == XCD (round-robin dispatch heuristic)
    const int NX  = gridDim.x;
    const int id  = blockIdx.y * NX + blockIdx.x;
    const int xcd = id & 7, slot = id >> 3;
    const int ngx = NX / cn;                 // #col-groups of XCD rectangles
    const int rg = xcd / ngx, cg = xcd - rg * ngx;
    const int m0 = (rg * cm + (slot % cm)) * 128;
    const int n0 = (cg * cn + (slot / cm)) * 128;
    const int wm = (wv >> 1) << 6;
    const int wn = (wv & 1) << 6;

    const int rsub = lane >> 3;                    // 0..7 row within chunk
    const int cu8  = ((lane & 7) ^ rsub) * 8;      // swizzled source col (elems)
    const unsigned short* Ag = A  + (size_t)(m0 + wv * 32 + rsub) * K + cu8;
    const unsigned short* Bg = Wt + (size_t)(n0 + wv * 32 + rsub) * K + cu8;

    f32x4 acc[4][4];
#pragma unroll
    for (int i = 0; i < 4; i++)
#pragma unroll
        for (int j = 0; j < 4; j++) acc[i][j] = f32x4{0.f, 0.f, 0.f, 0.f};

    const int NT = K >> 6;

    // stage tile t into buffer b: 8 GLDS per wave (4 row-chunks x {A,B})
    auto stage = [&](int t, int b) {
        const int kb = t << 6;
#pragma unroll
        for (int r = 0; r < 4; r++) {
            GLDS(Ag + (size_t)(r * 8) * K + kb, &As[b][(wv * 4 + r) * 512]);
            GLDS(Bg + (size_t)(r * 8) * K + kb, &Bs[b][(wv * 4 + r) * 512]);
        }
    };

    // prologue: tiles 0 and 1 in flight
    stage(0, 0);
    if (NT > 1) stage(1, 1);

    for (int i = 0; i < NT; i++) {
        const int b = i % 3;
        if (i + 2 < NT) {
            stage(i + 2, (i + 2) % 3);
            // my tile-i loads done; tiles i+1, i+2 (8 GLDS each) stay in flight
            asm volatile("s_waitcnt vmcnt(16)" ::: "memory");
        } else if (i + 1 < NT) {
            asm volatile("s_waitcnt vmcnt(8)" ::: "memory");
        } else {
            asm volatile("s_waitcnt vmcnt(0)" ::: "memory");
        }
        __builtin_amdgcn_s_barrier();   // all waves' tile-i loads complete

        // compute buffer b: 2 K-slices x 16 MFMA
#pragma unroll
        for (int ks = 0; ks < 2; ks++) {
            short8 af[4], bfr[4];
#pragma unroll
            for (int mi = 0; mi < 4; mi++)
                af[mi] = *(const short8*)(&As[b][(wm + mi * 16 + l16) * 64 +
                             (((ks * 4 + quad) ^ (l16 & 7)) * 8)]);
#pragma unroll
            for (int ni = 0; ni < 4; ni++)
                bfr[ni] = *(const short8*)(&Bs[b][(wn + ni * 16 + l16) * 64 +
                             (((ks * 4 + quad) ^ (l16 & 7)) * 8)]);
#pragma unroll
            for (int mi = 0; mi < 4; mi++)
#pragma unroll
                for (int ni = 0; ni < 4; ni++)
                    acc[mi][ni] = __builtin_amdgcn_mfma_f32_16x16x32_bf16(
                        af[mi], bfr[ni], acc[mi][ni], 0, 0, 0);
        }
        // my LDS reads of buffer b complete -> after barrier, b is reusable
        asm volatile("s_waitcnt lgkmcnt(0)" ::: "memory");
        __builtin_amdgcn_s_barrier();
    }

    // epilogue: bias + fused residual, fp32 out
#pragma unroll
    for (int mi = 0; mi < 4; mi++)
#pragma unroll
        for (int ni = 0; ni < 4; ni++) {
            const int colg = n0 + wn + ni * 16 + l16;
            const float bv = b0[colg];
#pragma unroll
            for (int r = 0; r < 4; r++) {
                const int rowg = m0 + wm + mi * 16 + quad * 4 + r;
                outf[(size_t)rowg * N + colg] =
                    acc[mi][ni][r] + bv + res[(size_t)rowg * N + colg];
            }
        }
}

// ---------------------------------------------------------------------------
// Flash attention v4: 128 queries/block (32/wave). Q (pre-scaled), K:
// [B,H,S,64]; VT: [B,H,64,S]; O: [B,S,1024] bf16.
// Fixed-shift base-2 softmax; register prefetch of next K/V tile; Ps
// XOR-swizzled. Causal: blockIdx remapped so co-resident block pairs have
// constant total work (kills the straggler imbalance).
// ---------------------------------------------------------------------------
template <bool CAUSAL>
__global__ __launch_bounds__(256, 2)
void attn4_kernel(const unsigned short* __restrict__ Q,
                  const unsigned short* __restrict__ K,
                  const unsigned short* __restrict__ VT,
                  unsigned short* __restrict__ O)
{
    __shared__ unsigned short Ks[128 * 72];
    __shared__ unsigned short Vt[64 * 136];
    __shared__ unsigned short Ps[4][32 * 136];
    __shared__ float sumS[4][32];
    const int tid  = threadIdx.x;
    const int lane = tid & 63;
    const int wave = tid >> 6;
    const int quad = lane >> 4;
    const int l16  = lane & 15;
    const int bh = blockIdx.y;
    // causal: pair heavy with light so each CU's two blocks sum to 17 tiles
    const int qb = (CAUSAL && (bh & 16)) ? (15 - (int)blockIdx.x) : (int)blockIdx.x;
    const int q0 = qb * 128;
    const size_t baseK = (size_t)bh * SEQ * 64;
    const size_t baseV = (size_t)bh * 64 * SEQ;

    short8 aq[2][2];
#pragma unroll
    for (int qs = 0; qs < 2; qs++) {
        const unsigned short* qp =
            Q + baseK + (size_t)(q0 + wave * 32 + qs * 16 + l16) * 64 + quad * 8;
        aq[qs][0] = *(const short8*)(qp);
        aq[qs][1] = *(const short8*)(qp + 32);
    }
    f32x4 acc[4][2];   // [mi(d)][qs]: O^T row d=mi*16+quad*4+r, col q=l16
#pragma unroll
    for (int i = 0; i < 4; i++)
#pragma unroll
        for (int j = 0; j < 2; j++) acc[i][j] = f32x4{0.f, 0.f, 0.f, 0.f};
    float lsum[2][4] = {{0.f, 0.f, 0.f, 0.f}, {0.f, 0.f, 0.f, 0.f}};

    const int nkb = CAUSAL ? (qb + 1) : (SEQ / 128);
    const int krow = tid >> 1;
    const int kc   = (tid & 1) * 32;
    const int vrow = tid >> 2;
    const int vc   = (tid & 3) * 32;
    const unsigned short* kg = K  + baseK + (size_t)krow * 64 + kc;
    const unsigned short* vg = VT + baseV + (size_t)vrow * SEQ + vc;

    short8 kr0 = *(const short8*)(kg),      kr1 = *(const short8*)(kg + 8);
    short8 kr2 = *(const short8*)(kg + 16), kr3 = *(const short8*)(kg + 24);
    short8 vr0 = *(const short8*)(vg),      vr1 = *(const short8*)(vg + 8);
    short8 vr2 = *(const short8*)(vg + 16), vr3 = *(const short8*)(vg + 24);

    for (int kb = 0; kb < nkb; kb++) {
        __syncthreads();
        *(short8*)&Ks[krow * 72 + kc]      = kr0;
        *(short8*)&Ks[krow * 72 + kc + 8]  = kr1;
        *(short8*)&Ks[krow * 72 + kc + 16] = kr2;
        *(short8*)&Ks[krow * 72 + kc + 24] = kr3;
        *(short8*)&Vt[vrow * 136 + vc]      = vr0;
        *(short8*)&Vt[vrow * 136 + vc + 8]  = vr1;
        *(short8*)&Vt[vrow * 136 + vc + 16] = vr2;
        *(short8*)&Vt[vrow * 136 + vc + 24] = vr3;
        if (kb + 1 < nkb) {
            const unsigned short* kg2 = kg + (size_t)(kb + 1) * 128 * 64;
            const unsigned short* vg2 = vg + (size_t)(kb + 1) * 128;
            kr0 = *(const short8*)(kg2);      kr1 = *(const short8*)(kg2 + 8);
            kr2 = *(const short8*)(kg2 + 16); kr3 = *(const short8*)(kg2 + 24);
            vr0 = *(const short8*)(vg2);      vr1 = *(const short8*)(vg2 + 8);
            vr2 = *(const short8*)(vg2 + 16); vr3 = *(const short8*)(vg2 + 24);
        }
        __syncthreads();

        const bool maskTile = CAUSAL && (kb == nkb - 1);
#pragma unroll
        for (int qs = 0; qs < 2; qs++) {
            f32x4 scf[8];
#pragma unroll
            for (int nt = 0; nt < 8; nt++) {
                f32x4 z = f32x4{0.f, 0.f, 0.f, 0.f};
#pragma unroll
                for (int c = 0; c < 2; c++) {
                    short8 bk = *(const short8*)(&Ks[(nt * 16 + l16) * 72 + c * 32 + quad * 8]);
                    z = __builtin_amdgcn_mfma_f32_16x16x32_bf16(aq[qs][c], bk, z, 0, 0, 0);
                }
                scf[nt] = z;
            }
            if (maskTile) {
                const int qg = q0 + wave * 32 + qs * 16 + quad * 4;
                const int k0 = kb * 128;
#pragma unroll
                for (int nt = 0; nt < 8; nt++) {
                    const int kg_ = k0 + nt * 16 + l16;
#pragma unroll
                    for (int r = 0; r < 4; r++)
                        if (kg_ > qg + r) scf[nt][r] = -1e9f;
                }
            }
#pragma unroll
            for (int nt = 0; nt < 8; nt++)
#pragma unroll
                for (int r = 0; r < 4; r++) {
                    float pv = EXP2(scf[nt][r] - PSHIFT);
                    lsum[qs][r] += pv;
                    Ps[wave][(qs * 16 + quad * 4 + r) * 136 +
                             ((nt * 16 + l16) ^ (quad * 8))] = f2bf(pv);
                }
        }
        // O^T += V^T @ P^T, both operands contiguous b128; Vt reads shared
        const int pswz = 8 * (quad ^ ((l16 >> 2) & 3));
#pragma unroll
        for (int c = 0; c < 4; c++) {
            short8 av[4];
#pragma unroll
            for (int mi = 0; mi < 4; mi++)
                av[mi] = *(const short8*)(&Vt[(mi * 16 + l16) * 136 + c * 32 + quad * 8]);
#pragma unroll
            for (int qs = 0; qs < 2; qs++) {
                short8 bp = *(const short8*)(&Ps[wave][(qs * 16 + l16) * 136 + c * 32 + pswz]);
#pragma unroll
                for (int mi = 0; mi < 4; mi++)
                    acc[mi][qs] = __builtin_amdgcn_mfma_f32_16x16x32_bf16(av[mi], bp, acc[mi][qs], 0, 0, 0);
            }
        }
    }
#pragma unroll
    for (int qs = 0; qs < 2; qs++)
#pragma unroll
        for (int r = 0; r < 4; r++) {
#pragma unroll
            for (int off = 1; off < 16; off <<= 1)
                lsum[qs][r] += __shfl_xor(lsum[qs][r], off, 64);
        }
    if (l16 == 0) {
#pragma unroll
        for (int qs = 0; qs < 2; qs++)
#pragma unroll
            for (int r = 0; r < 4; r++)
                sumS[wave][qs * 16 + quad * 4 + r] = lsum[qs][r];
    }
    __syncthreads();
    const int b = bh >> 4, h = bh & 15;
#pragma unroll
    for (int qs = 0; qs < 2; qs++) {
        const float rcpL = 1.f / sumS[wave][qs * 16 + l16];
        const int qg = q0 + wave * 32 + qs * 16 + l16;
#pragma unroll
        for (int mi = 0; mi < 4; mi++) {
            ushort4 o4;
            o4.x = f2bf(acc[mi][qs][0] * rcpL);
            o4.y = f2bf(acc[mi][qs][1] * rcpL);
            o4.z = f2bf(acc[mi][qs][2] * rcpL);
            o4.w = f2bf(acc[mi][qs][3] * rcpL);
            *(ushort4*)&O[(size_t)(b * SEQ + qg) * 1024 + h * 64 + mi * 16 + quad * 4] = o4;
        }
    }
}

// ---------------------------------------------------------------------------
extern "C" void kernel_launch(void* const* d_in, const int* in_sizes, int n_in,
                              void* d_out, int out_size, void* d_ws, size_t ws_size,
                              hipStream_t stream)
{
    (void)in_sizes; (void)n_in; (void)out_size; (void)ws_size;
    const int B = 2, S = SEQ, D = 1024, DFF = 4096;
    const int M = B * S;  // 4096

    const float* x     = (const float*)d_in[0];
    const float* enc   = (const float*)d_in[1];
    const float* sa_wq = (const float*)d_in[4],  *sa_bq = (const float*)d_in[5];
    const float* sa_wk = (const float*)d_in[6],  *sa_bk = (const float*)d_in[7];
    const float* sa_wv = (const float*)d_in[8],  *sa_bv = (const float*)d_in[9];
    const float* sa_wo = (const float*)d_in[10], *sa_bo = (const float*)d_in[11];
    const float* ca_wq = (const float*)d_in[12], *ca_bq = (const float*)d_in[13];
    const float* ca_wk = (const float*)d_in[14], *ca_bk = (const float*)d_in[15];
    const float* ca_wv = (const float*)d_in[16], *ca_bv = (const float*)d_in[17];
    const float* ca_wo = (const float*)d_in[18], *ca_bo = (const float*)d_in[19];
    const float* ff_w1 = (const float*)d_in[20], *ff_b1 = (const float*)d_in[21];
    const float* ff_w2 = (const float*)d_in[22], *ff_b2 = (const float*)d_in[23];
    const float* n1_g  = (const float*)d_in[24], *n1_b = (const float*)d_in[25];
    const float* n2_g  = (const float*)d_in[26], *n2_b = (const float*)d_in[27];
    const float* n3_g  = (const float*)d_in[28], *n3_b = (const float*)d_in[29];
    float* out = (float*)d_out;

    char* p = (char*)d_ws;
    auto carve = [&](size_t bytes) -> char* {
        char* r = p;
        p += (bytes + 255) & ~(size_t)255;
        return r;
    };
    unsigned short* wt8     = (unsigned short*)carve((size_t)8 * D * D * 2);
    unsigned short* wt_sqkv = wt8;                       // saq, sak, sav contiguous
    unsigned short* wt_sao  = wt8 + (size_t)3 * D * D;
    unsigned short* wt_cqkv = wt8 + (size_t)4 * D * D;   // caq, cak, cav contiguous
    unsigned short* wt_cao  = wt8 + (size_t)7 * D * D;
    unsigned short* wt_ff1  = (unsigned short*)carve((size_t)D * DFF * 2);
    unsigned short* wt_ff2  = (unsigned short*)carve((size_t)DFF * D * 2);
    unsigned short* encb    = (unsigned short*)carve((size_t)M * D * 2);
    unsigned short* hb      = (unsigned short*)carve((size_t)M * D * 2);
    unsigned short* qbuf    = (unsigned short*)carve((size_t)M * D * 2);
    unsigned short* kbuf    = (unsigned short*)carve((size_t)M * D * 2);
    unsigned short* vtbuf   = (unsigned short*)carve((size_t)M * D * 2);
    unsigned short* ffh     = (unsigned short*)carve((size_t)M * DFF * 2);
    float* x1 = (float*)carve((size_t)M * D * 4);
    unsigned short* abuf = hb;   // lifetimes disjoint
    float* x2 = out;             // block-2 residual in d_out; block-3 in-place

    dim3 blk(256);
    wtrans8_kernel<<<dim3(32, 32, 8), blk, 0, stream>>>(
        sa_wq, sa_wk, sa_wv, sa_wo, ca_wq, ca_wk, ca_wv, ca_wo, wt8);
    wtrans_kernel<<<dim3(DFF / 32, D / 32), blk, 0, stream>>>(ff_w1, wt_ff1, D, DFF);
    wtrans_kernel<<<dim3(D / 32, DFF / 32), blk, 0, stream>>>(ff_w2, wt_ff2, DFF, D);
    cvt_kernel<<<dim3(M * D / 1024), blk, 0, stream>>>(enc, encb, M * D);

    // ---- block 1: self-attention ----
    ln_kernel<<<dim3(M), blk, 0, stream>>>(x, n1_g, n1_b, hb);
    gemm_kernel<1><<<dim3(3 * D / 128, M / 128), blk, 0, stream>>>(
        hb, hb, wt_sqkv, sa_bq, sa_bk, sa_bv, qbuf, kbuf, vtbuf, M, 3 * D, D);
    attn4_kernel<true><<<dim3(S / 128, B * 16), blk, 0, stream>>>(qbuf, kbuf, vtbuf, abuf);
    gemm_db_kernel<<<dim3(D / 128, M / 128), blk, 0, stream>>>(
        abuf, wt_sao, sa_bo, x, x1, M, D, D, 8, 4);

    // ---- block 2: cross-attention (Q from hb, K/V from encoder) ----
    ln_kernel<<<dim3(M), blk, 0, stream>>>(x1, n2_g, n2_b, hb);
    gemm_kernel<1><<<dim3(3 * D / 128, M / 128), blk, 0, stream>>>(
        hb, encb, wt_cqkv, ca_bq, ca_bk, ca_bv, qbuf, kbuf, vtbuf, M, 3 * D, D);
    attn4_kernel<false><<<dim3(S / 128, B * 16), blk, 0, stream>>>(qbuf, kbuf, vtbuf, abuf);
    gemm_db_kernel<<<dim3(D / 128, M / 128), blk, 0, stream>>>(
        abuf, wt_cao, ca_bo, x1, x2, M, D, D, 8, 4);

    // ---- block 3: feed-forward ----
    ln_kernel<<<dim3(M), blk, 0, stream>>>(x2, n3_g, n3_b, hb);
    gemm_kernel<2><<<dim3(DFF / 128, M / 128), blk, 0, stream>>>(
        hb, hb, wt_ff1, ff_b1, nullptr, nullptr, ffh, nullptr, nullptr, M, DFF, D);
    gemm_db_kernel<<<dim3(D / 128, M / 128), blk, 0, stream>>>(
        ffh, wt_ff2, ff_b2, x2, out, M, D, DFF, 4, 8);
}

// Round 4
// 582.167 us; speedup vs baseline: 1.0402x; 1.0208x over previous
//
#include <hip/hip_runtime.h>

typedef short short8 __attribute__((ext_vector_type(8)));
typedef float f32x4 __attribute__((ext_vector_type(4)));

#define SEQ 2048
#define QSCALE 0.18033688011112042f   // 0.125 * log2(e): softmax done in base 2
#define PSHIFT 20.0f                  // fixed softmax shift (cancels in O = acc/l)
#define EXP2(x) __builtin_amdgcn_exp2f(x)

// async global->LDS, 16B per lane; lds base must be wave-uniform
#define GLDS(g, l) __builtin_amdgcn_global_load_lds( \
    (const __attribute__((address_space(1))) unsigned int*)(g), \
    (__attribute__((address_space(3))) unsigned int*)(l), 16, 0, 0)

__device__ __forceinline__ unsigned short f2bf(float f) {
    unsigned int u = __builtin_bit_cast(unsigned int, f);
    unsigned int r = (u + 0x7fffu + ((u >> 16) & 1u)) >> 16;
    return (unsigned short)r;
}

// ---------------------------------------------------------------------------
// Batched weight transpose + fp32->bf16: 8 D x D weights in one launch.
// ---------------------------------------------------------------------------
__global__ __launch_bounds__(256)
void wtrans8_kernel(const float* w0, const float* w1, const float* w2, const float* w3,
                    const float* w4, const float* w5, const float* w6, const float* w7,
                    unsigned short* __restrict__ outbase)
{
    const float* Ws[8] = {w0, w1, w2, w3, w4, w5, w6, w7};
    const float* __restrict__ W = Ws[blockIdx.z];
    unsigned short* __restrict__ Wt = outbase + (size_t)blockIdx.z * 1024 * 1024;
    __shared__ float t[32][33];
    const int tx = threadIdx.x & 31;
    const int ty = threadIdx.x >> 5;
    const int nb = blockIdx.x * 32;
    const int kb = blockIdx.y * 32;
#pragma unroll
    for (int i = 0; i < 4; i++)
        t[ty + i * 8][tx] = W[(size_t)(kb + ty + i * 8) * 1024 + nb + tx];
    __syncthreads();
#pragma unroll
    for (int i = 0; i < 4; i++)
        Wt[(size_t)(nb + ty + i * 8) * 1024 + kb + tx] = f2bf(t[tx][ty + i * 8]);
}

// single weight transpose (for the two FFN shapes)
__global__ __launch_bounds__(256)
void wtrans_kernel(const float* __restrict__ W, unsigned short* __restrict__ Wt,
                   int Kd, int Nd)
{
    __shared__ float t[32][33];
    const int tx = threadIdx.x & 31;
    const int ty = threadIdx.x >> 5;
    const int nb = blockIdx.x * 32;
    const int kb = blockIdx.y * 32;
#pragma unroll
    for (int i = 0; i < 4; i++)
        t[ty + i * 8][tx] = W[(size_t)(kb + ty + i * 8) * Nd + nb + tx];
    __syncthreads();
#pragma unroll
    for (int i = 0; i < 4; i++)
        Wt[(size_t)(nb + ty + i * 8) * Kd + kb + tx] = f2bf(t[tx][ty + i * 8]);
}

// ---------------------------------------------------------------------------
// Elementwise fp32 -> bf16
// ---------------------------------------------------------------------------
__global__ __launch_bounds__(256)
void cvt_kernel(const float* __restrict__ in, unsigned short* __restrict__ out, int n)
{
    int i = (blockIdx.x * 256 + threadIdx.x) * 4;
    if (i < n) {
        float4 v = *(const float4*)(in + i);
        ushort4 o;
        o.x = f2bf(v.x); o.y = f2bf(v.y); o.z = f2bf(v.z); o.w = f2bf(v.w);
        *(ushort4*)(out + i) = o;
    }
}

// ---------------------------------------------------------------------------
// LayerNorm (torch-faithful: ddof=1, eps added to std). fp32 in -> bf16 out.
// ---------------------------------------------------------------------------
__global__ __launch_bounds__(256)
void ln_kernel(const float* __restrict__ x, const float* __restrict__ g,
               const float* __restrict__ bb, unsigned short* __restrict__ out)
{
    const int D = 1024;
    const int row = blockIdx.x;
    const float* xr = x + (size_t)row * D;
    float v[4];
    float s = 0.f, ss = 0.f;
#pragma unroll
    for (int i = 0; i < 4; i++) {
        v[i] = xr[threadIdx.x + i * 256];
        s += v[i];
        ss += v[i] * v[i];
    }
#pragma unroll
    for (int off = 1; off < 64; off <<= 1) {
        s  += __shfl_xor(s,  off, 64);
        ss += __shfl_xor(ss, off, 64);
    }
    __shared__ float red[8];
    const int wave = threadIdx.x >> 6;
    if ((threadIdx.x & 63) == 0) { red[wave] = s; red[4 + wave] = ss; }
    __syncthreads();
    s  = red[0] + red[1] + red[2] + red[3];
    ss = red[4] + red[5] + red[6] + red[7];
    float mean = s / D;
    float var  = fmaxf((ss - s * mean) / (D - 1), 0.f);
    float inv  = 1.f / (sqrtf(var) + 1e-6f);
#pragma unroll
    for (int i = 0; i < 4; i++) {
        int c = threadIdx.x + i * 256;
        out[(size_t)row * D + c] = f2bf(g[c] * (v[i] - mean) * inv + bb[c]);
    }
}

// ---------------------------------------------------------------------------
// Tiled MFMA GEMM (m97 structure): C[M,N] = A[M,K] @ Wt[N,K]^T + bias
// 128x128 tile, BK=32, unpadded LDS, global_load_lds 16B async staging.
// MODE 1: projection GEMM. Section = n0>>10: 0 -> Q (from A, scaled QSCALE,
//         head layout [B,H,S,64]); 1 -> K (from A2, head layout);
//         2 -> V (from A2, written TRANSPOSED [B,H,64,S] as packed ushort4).
// MODE 2: relu -> bf16 row-major [M,N]    (FFN first GEMM, o0)
// ---------------------------------------------------------------------------
template <int MODE>
__global__ __launch_bounds__(256)
void gemm_kernel(const unsigned short* __restrict__ A,
                 const unsigned short* __restrict__ A2,
                 const unsigned short* __restrict__ Wt,
                 const float* __restrict__ b0,
                 const float* __restrict__ b1,
                 const float* __restrict__ b2,
                 unsigned short* __restrict__ o0,
                 unsigned short* __restrict__ o1,
                 unsigned short* __restrict__ o2,
                 int M, int N, int K)
{
    __shared__ unsigned short As[128 * 32];
    __shared__ unsigned short Bs[128 * 32];
    const int tid  = threadIdx.x;
    const int lane = tid & 63;
    const int wv   = tid >> 6;
    const int quad = lane >> 4;
    const int l16  = lane & 15;
    const int m0 = blockIdx.y * 128;
    const int n0 = blockIdx.x * 128;
    const int wm = (wv >> 1) << 6;
    const int wn = (wv & 1) << 6;
    const int sect = (MODE == 1) ? (n0 >> 10) : 0;
    const unsigned short* Asel = (MODE == 1 && sect != 0) ? A2 : A;

    const int srow0 = wv * 32 + (lane >> 2);
    const int srow1 = srow0 + 16;
    const int scol8 = (lane & 3) * 8;
    unsigned short* asw0 = &As[(wv * 2 + 0) * 512];
    unsigned short* asw1 = &As[(wv * 2 + 1) * 512];
    unsigned short* bsw0 = &Bs[(wv * 2 + 0) * 512];
    unsigned short* bsw1 = &Bs[(wv * 2 + 1) * 512];
    const unsigned short* Ag0 = Asel + (size_t)(m0 + srow0) * K + scol8;
    const unsigned short* Ag1 = Asel + (size_t)(m0 + srow1) * K + scol8;
    const unsigned short* Bg0 = Wt   + (size_t)(n0 + srow0) * K + scol8;
    const unsigned short* Bg1 = Wt   + (size_t)(n0 + srow1) * K + scol8;

    f32x4 acc[4][4];
#pragma unroll
    for (int i = 0; i < 4; i++)
#pragma unroll
        for (int j = 0; j < 4; j++) acc[i][j] = f32x4{0.f, 0.f, 0.f, 0.f};

    for (int k0 = 0; k0 < K; k0 += 32) {
        GLDS(Ag0 + k0, asw0);
        GLDS(Ag1 + k0, asw1);
        GLDS(Bg0 + k0, bsw0);
        GLDS(Bg1 + k0, bsw1);
        __syncthreads();
        short8 af[4], bfr[4];
#pragma unroll
        for (int i = 0; i < 4; i++)
            af[i] = *(const short8*)(&As[(wm + i * 16 + l16) * 32 + quad * 8]);
#pragma unroll
        for (int i = 0; i < 4; i++)
            bfr[i] = *(const short8*)(&Bs[(wn + i * 16 + l16) * 32 + quad * 8]);
#pragma unroll
        for (int mi = 0; mi < 4; mi++)
#pragma unroll
            for (int ni = 0; ni < 4; ni++)
                acc[mi][ni] = __builtin_amdgcn_mfma_f32_16x16x32_bf16(
                    af[mi], bfr[ni], acc[mi][ni], 0, 0, 0);
        __syncthreads();
    }

    if (MODE == 1) {
        const float* bias = (sect == 0) ? b0 : ((sect == 1) ? b1 : b2);
        if (sect == 2) {
            // V: write transposed [B,H,64,S], 4 consecutive s packed per store
#pragma unroll
            for (int mi = 0; mi < 4; mi++)
#pragma unroll
                for (int ni = 0; ni < 4; ni++) {
                    const int cc = (n0 + wn + ni * 16 + l16) & 1023;
                    const int h = cc >> 6, d = cc & 63;
                    const float bv = bias[cc];
                    const int rowg = m0 + wm + mi * 16 + quad * 4;
                    const int b = rowg >> 11, s = rowg & 2047;
                    ushort4 o4;
                    o4.x = f2bf(acc[mi][ni][0] + bv);
                    o4.y = f2bf(acc[mi][ni][1] + bv);
                    o4.z = f2bf(acc[mi][ni][2] + bv);
                    o4.w = f2bf(acc[mi][ni][3] + bv);
                    *(ushort4*)&o2[((size_t)(b * 16 + h) * 64 + d) * SEQ + s] = o4;
                }
        } else {
            unsigned short* dst = (sect == 0) ? o0 : o1;
            const float scl = (sect == 0) ? QSCALE : 1.0f;
#pragma unroll
            for (int mi = 0; mi < 4; mi++)
#pragma unroll
                for (int ni = 0; ni < 4; ni++) {
                    const int cc = (n0 + wn + ni * 16 + l16) & 1023;
                    const int h = cc >> 6, d = cc & 63;
                    const float bv = bias[cc];
#pragma unroll
                    for (int r = 0; r < 4; r++) {
                        const int rowg = m0 + wm + mi * 16 + quad * 4 + r;
                        const int b = rowg >> 11, s = rowg & 2047;
                        float v = (acc[mi][ni][r] + bv) * scl;
                        dst[((size_t)(b * 16 + h) * SEQ + s) * 64 + d] = f2bf(v);
                    }
                }
        }
    } else {
#pragma unroll
        for (int mi = 0; mi < 4; mi++)
#pragma unroll
            for (int ni = 0; ni < 4; ni++) {
                const int colg = n0 + wn + ni * 16 + l16;
                const float bv = b0[colg];
#pragma unroll
                for (int r = 0; r < 4; r++) {
                    const int rowg = m0 + wm + mi * 16 + quad * 4 + r;
                    float v = acc[mi][ni][r] + bv;
                    o0[(size_t)rowg * N + colg] = f2bf(fmaxf(v, 0.f));
                }
            }
    }
}

// ---------------------------------------------------------------------------
// Register-staged double-buffered GEMM for the N=1024 shapes.
// C[M,N] = A[M,K] @ Wt[N,K]^T + bias + res   (fp32 out, fused residual)
// 128x128 tile, BK=64, 4 waves, 2 LDS buffers.
// TRANSPORT EXPERIMENT (T14): per-lane global_load_dwordx4 -> VGPR, issued
// BEFORE the compute phase (HBM/L3 latency hides under 32 MFMAs), then
// vmcnt(0) + linear ds_write_b128 after compute. The LDS byte image,
// the XOR read swizzle, and the pre-swizzled global source addresses are
// IDENTICAL to the GLDS version -- only the transport changed (prior rounds
// measured GLDS resolving ~1/90cy/CU regardless of pipeline depth).
// One barrier per K-step.
// XCD rectangle partition (cm x cn tiles per XCD) kept from round 3
// (FETCH 143 -> 57 MB verified).
// ---------------------------------------------------------------------------
__global__ __launch_bounds__(256, 1)
void gemm_db_kernel(const unsigned short* __restrict__ A,
                    const unsigned short* __restrict__ Wt,
                    const float* __restrict__ b0,
                    const float* __restrict__ res,
                    float* __restrict__ outf,
                    int M, int N, int K, int cm, int cn)
{
    __shared__ unsigned short As[2][128 * 64];
    __shared__ unsigned short Bs[2][128 * 64];
    const int tid  = threadIdx.x;
    const int lane = tid & 63;
    const int wv   = tid >> 6;
    const int quad = lane >> 4;
    const int l16  = lane & 15;
    // XCD partition: id%8 == XCD (round-robin dispatch heuristic)
    const int NX  = gridDim.x;
    const int id  = blockIdx.y * NX + blockIdx.x;
    const int xcd = id & 7, slot = id >> 3;
    const int ngx = NX / cn;                 // #col-groups of XCD rectangles
    const int rg = xcd / ngx, cg = xcd - rg * ngx;
    const int m0 = (rg * cm + (slot % cm)) * 128;
    const int n0 = (cg * cn + (slot / cm)) * 128;
    const int wm = (wv >> 1) << 6;
    const int wn = (wv & 1) << 6;

    const int rsub = lane >> 3;                    // 0..7 row within chunk
    const int cu8  = ((lane & 7) ^ rsub) * 8;      // swizzled source col (elems)
    const unsigned short* Ag = A  + (size_t)(m0 + wv * 32 + rsub) * K + cu8;
    const unsigned short* Bg = Wt + (size_t)(n0 + wv * 32 + rsub) * K + cu8;

    f32x4 acc[4][4];
#pragma unroll
    for (int i = 0; i < 4; i++)
#pragma unroll
        for (int j = 0; j < 4; j++) acc[i][j] = f32x4{0.f, 0.f, 0.f, 0.f};

    const int NT = K >> 6;

    short8 ar[4], br[4];   // in-flight staging registers (one tile)

    // load tile t into regs (8 x dwordx4 per lane-row-chunk pattern)
    auto ldregs = [&](int t) {
        const int kb = t << 6;
#pragma unroll
        for (int r = 0; r < 4; r++) {
            ar[r] = *(const short8*)(Ag + (size_t)(r * 8) * K + kb);
            br[r] = *(const short8*)(Bg + (size_t)(r * 8) * K + kb);
        }
    };
    // write staged regs into LDS buffer b (linear chunks, zero conflicts)
    auto wrlds = [&](int b) {
#pragma unroll
        for (int r = 0; r < 4; r++) {
            *(short8*)&As[b][(wv * 4 + r) * 512 + lane * 8] = ar[r];
            *(short8*)&Bs[b][(wv * 4 + r) * 512 + lane * 8] = br[r];
        }
    };

    // prologue: tile 0 -> regs -> LDS[0]
    ldregs(0);
    asm volatile("s_waitcnt vmcnt(0)" ::: "memory");
    wrlds(0);
    asm volatile("s_waitcnt lgkmcnt(0)" ::: "memory");
    __builtin_amdgcn_s_barrier();

    for (int i = 0; i < NT; i++) {
        const int cur = i & 1;
        if (i + 1 < NT) ldregs(i + 1);   // issue early: latency under compute

        // compute buffer cur: 2 K-slices x 16 MFMA
#pragma unroll
        for (int ks = 0; ks < 2; ks++) {
            short8 af[4], bfr[4];
#pragma unroll
            for (int mi = 0; mi < 4; mi++)
                af[mi] = *(const short8*)(&As[cur][(wm + mi * 16 + l16) * 64 +
                             (((ks * 4 + quad) ^ (l16 & 7)) * 8)]);
#pragma unroll
            for (int ni = 0; ni < 4; ni++)
                bfr[ni] = *(const short8*)(&Bs[cur][(wn + ni * 16 + l16) * 64 +
                             (((ks * 4 + quad) ^ (l16 & 7)) * 8)]);
#pragma unroll
            for (int mi = 0; mi < 4; mi++)
#pragma unroll
                for (int ni = 0; ni < 4; ni++)
                    acc[mi][ni] = __builtin_amdgcn_mfma_f32_16x16x32_bf16(
                        af[mi], bfr[ni], acc[mi][ni], 0, 0, 0);
        }

        if (i + 1 < NT) {
            // regs arrived during compute; publish to the other buffer
            asm volatile("s_waitcnt vmcnt(0)" ::: "memory");
            wrlds(cur ^ 1);
            asm volatile("s_waitcnt lgkmcnt(0)" ::: "memory");
            __builtin_amdgcn_s_barrier();   // buffer cur^1 ready for all
        }
    }

    // epilogue: bias + fused residual, fp32 out
#pragma unroll
    for (int mi = 0; mi < 4; mi++)
#pragma unroll
        for (int ni = 0; ni < 4; ni++) {
            const int colg = n0 + wn + ni * 16 + l16;
            const float bv = b0[colg];
#pragma unroll
            for (int r = 0; r < 4; r++) {
                const int rowg = m0 + wm + mi * 16 + quad * 4 + r;
                outf[(size_t)rowg * N + colg] =
                    acc[mi][ni][r] + bv + res[(size_t)rowg * N + colg];
            }
        }
}

// ---------------------------------------------------------------------------
// Flash attention v4: 128 queries/block (32/wave). Q (pre-scaled), K:
// [B,H,S,64]; VT: [B,H,64,S]; O: [B,S,1024] bf16.
// Fixed-shift base-2 softmax; register prefetch of next K/V tile; Ps
// XOR-swizzled. Causal: blockIdx remapped so co-resident block pairs have
// constant total work (kills the straggler imbalance).
// ---------------------------------------------------------------------------
template <bool CAUSAL>
__global__ __launch_bounds__(256, 2)
void attn4_kernel(const unsigned short* __restrict__ Q,
                  const unsigned short* __restrict__ K,
                  const unsigned short* __restrict__ VT,
                  unsigned short* __restrict__ O)
{
    __shared__ unsigned short Ks[128 * 72];
    __shared__ unsigned short Vt[64 * 136];
    __shared__ unsigned short Ps[4][32 * 136];
    __shared__ float sumS[4][32];
    const int tid  = threadIdx.x;
    const int lane = tid & 63;
    const int wave = tid >> 6;
    const int quad = lane >> 4;
    const int l16  = lane & 15;
    const int bh = blockIdx.y;
    // causal: pair heavy with light so each CU's two blocks sum to 17 tiles
    const int qb = (CAUSAL && (bh & 16)) ? (15 - (int)blockIdx.x) : (int)blockIdx.x;
    const int q0 = qb * 128;
    const size_t baseK = (size_t)bh * SEQ * 64;
    const size_t baseV = (size_t)bh * 64 * SEQ;

    short8 aq[2][2];
#pragma unroll
    for (int qs = 0; qs < 2; qs++) {
        const unsigned short* qp =
            Q + baseK + (size_t)(q0 + wave * 32 + qs * 16 + l16) * 64 + quad * 8;
        aq[qs][0] = *(const short8*)(qp);
        aq[qs][1] = *(const short8*)(qp + 32);
    }
    f32x4 acc[4][2];   // [mi(d)][qs]: O^T row d=mi*16+quad*4+r, col q=l16
#pragma unroll
    for (int i = 0; i < 4; i++)
#pragma unroll
        for (int j = 0; j < 2; j++) acc[i][j] = f32x4{0.f, 0.f, 0.f, 0.f};
    float lsum[2][4] = {{0.f, 0.f, 0.f, 0.f}, {0.f, 0.f, 0.f, 0.f}};

    const int nkb = CAUSAL ? (qb + 1) : (SEQ / 128);
    const int krow = tid >> 1;
    const int kc   = (tid & 1) * 32;
    const int vrow = tid >> 2;
    const int vc   = (tid & 3) * 32;
    const unsigned short* kg = K  + baseK + (size_t)krow * 64 + kc;
    const unsigned short* vg = VT + baseV + (size_t)vrow * SEQ + vc;

    short8 kr0 = *(const short8*)(kg),      kr1 = *(const short8*)(kg + 8);
    short8 kr2 = *(const short8*)(kg + 16), kr3 = *(const short8*)(kg + 24);
    short8 vr0 = *(const short8*)(vg),      vr1 = *(const short8*)(vg + 8);
    short8 vr2 = *(const short8*)(vg + 16), vr3 = *(const short8*)(vg + 24);

    for (int kb = 0; kb < nkb; kb++) {
        __syncthreads();
        *(short8*)&Ks[krow * 72 + kc]      = kr0;
        *(short8*)&Ks[krow * 72 + kc + 8]  = kr1;
        *(short8*)&Ks[krow * 72 + kc + 16] = kr2;
        *(short8*)&Ks[krow * 72 + kc + 24] = kr3;
        *(short8*)&Vt[vrow * 136 + vc]      = vr0;
        *(short8*)&Vt[vrow * 136 + vc + 8]  = vr1;
        *(short8*)&Vt[vrow * 136 + vc + 16] = vr2;
        *(short8*)&Vt[vrow * 136 + vc + 24] = vr3;
        if (kb + 1 < nkb) {
            const unsigned short* kg2 = kg + (size_t)(kb + 1) * 128 * 64;
            const unsigned short* vg2 = vg + (size_t)(kb + 1) * 128;
            kr0 = *(const short8*)(kg2);      kr1 = *(const short8*)(kg2 + 8);
            kr2 = *(const short8*)(kg2 + 16); kr3 = *(const short8*)(kg2 + 24);
            vr0 = *(const short8*)(vg2);      vr1 = *(const short8*)(vg2 + 8);
            vr2 = *(const short8*)(vg2 + 16); vr3 = *(const short8*)(vg2 + 24);
        }
        __syncthreads();

        const bool maskTile = CAUSAL && (kb == nkb - 1);
#pragma unroll
        for (int qs = 0; qs < 2; qs++) {
            f32x4 scf[8];
#pragma unroll
            for (int nt = 0; nt < 8; nt++) {
                f32x4 z = f32x4{0.f, 0.f, 0.f, 0.f};
#pragma unroll
                for (int c = 0; c < 2; c++) {
                    short8 bk = *(const short8*)(&Ks[(nt * 16 + l16) * 72 + c * 32 + quad * 8]);
                    z = __builtin_amdgcn_mfma_f32_16x16x32_bf16(aq[qs][c], bk, z, 0, 0, 0);
                }
                scf[nt] = z;
            }
            if (maskTile) {
                const int qg = q0 + wave * 32 + qs * 16 + quad * 4;
                const int k0 = kb * 128;
#pragma unroll
                for (int nt = 0; nt < 8; nt++) {
                    const int kg_ = k0 + nt * 16 + l16;
#pragma unroll
                    for (int r = 0; r < 4; r++)
                        if (kg_ > qg + r) scf[nt][r] = -1e9f;
                }
            }
#pragma unroll
            for (int nt = 0; nt < 8; nt++)
#pragma unroll
                for (int r = 0; r < 4; r++) {
                    float pv = EXP2(scf[nt][r] - PSHIFT);
                    lsum[qs][r] += pv;
                    Ps[wave][(qs * 16 + quad * 4 + r) * 136 +
                             ((nt * 16 + l16) ^ (quad * 8))] = f2bf(pv);
                }
        }
        // O^T += V^T @ P^T, both operands contiguous b128; Vt reads shared
        const int pswz = 8 * (quad ^ ((l16 >> 2) & 3));
#pragma unroll
        for (int c = 0; c < 4; c++) {
            short8 av[4];
#pragma unroll
            for (int mi = 0; mi < 4; mi++)
                av[mi] = *(const short8*)(&Vt[(mi * 16 + l16) * 136 + c * 32 + quad * 8]);
#pragma unroll
            for (int qs = 0; qs < 2; qs++) {
                short8 bp = *(const short8*)(&Ps[wave][(qs * 16 + l16) * 136 + c * 32 + pswz]);
#pragma unroll
                for (int mi = 0; mi < 4; mi++)
                    acc[mi][qs] = __builtin_amdgcn_mfma_f32_16x16x32_bf16(av[mi], bp, acc[mi][qs], 0, 0, 0);
            }
        }
    }
#pragma unroll
    for (int qs = 0; qs < 2; qs++)
#pragma unroll
        for (int r = 0; r < 4; r++) {
#pragma unroll
            for (int off = 1; off < 16; off <<= 1)
                lsum[qs][r] += __shfl_xor(lsum[qs][r], off, 64);
        }
    if (l16 == 0) {
#pragma unroll
        for (int qs = 0; qs < 2; qs++)
#pragma unroll
            for (int r = 0; r < 4; r++)
                sumS[wave][qs * 16 + quad * 4 + r] = lsum[qs][r];
    }
    __syncthreads();
    const int b = bh >> 4, h = bh & 15;
#pragma unroll
    for (int qs = 0; qs < 2; qs++) {
        const float rcpL = 1.f / sumS[wave][qs * 16 + l16];
        const int qg = q0 + wave * 32 + qs * 16 + l16;
#pragma unroll
        for (int mi = 0; mi < 4; mi++) {
            ushort4 o4;
            o4.x = f2bf(acc[mi][qs][0] * rcpL);
            o4.y = f2bf(acc[mi][qs][1] * rcpL);
            o4.z = f2bf(acc[mi][qs][2] * rcpL);
            o4.w = f2bf(acc[mi][qs][3] * rcpL);
            *(ushort4*)&O[(size_t)(b * SEQ + qg) * 1024 + h * 64 + mi * 16 + quad * 4] = o4;
        }
    }
}

// ---------------------------------------------------------------------------
extern "C" void kernel_launch(void* const* d_in, const int* in_sizes, int n_in,
                              void* d_out, int out_size, void* d_ws, size_t ws_size,
                              hipStream_t stream)
{
    (void)in_sizes; (void)n_in; (void)out_size; (void)ws_size;
    const int B = 2, S = SEQ, D = 1024, DFF = 4096;
    const int M = B * S;  // 4096

    const float* x     = (const float*)d_in[0];
    const float* enc   = (const float*)d_in[1];
    const float* sa_wq = (const float*)d_in[4],  *sa_bq = (const float*)d_in[5];
    const float* sa_wk = (const float*)d_in[6],  *sa_bk = (const float*)d_in[7];
    const float* sa_wv = (const float*)d_in[8],  *sa_bv = (const float*)d_in[9];
    const float* sa_wo = (const float*)d_in[10], *sa_bo = (const float*)d_in[11];
    const float* ca_wq = (const float*)d_in[12], *ca_bq = (const float*)d_in[13];
    const float* ca_wk = (const float*)d_in[14], *ca_bk = (const float*)d_in[15];
    const float* ca_wv = (const float*)d_in[16], *ca_bv = (const float*)d_in[17];
    const float* ca_wo = (const float*)d_in[18], *ca_bo = (const float*)d_in[19];
    const float* ff_w1 = (const float*)d_in[20], *ff_b1 = (const float*)d_in[21];
    const float* ff_w2 = (const float*)d_in[22], *ff_b2 = (const float*)d_in[23];
    const float* n1_g  = (const float*)d_in[24], *n1_b = (const float*)d_in[25];
    const float* n2_g  = (const float*)d_in[26], *n2_b = (const float*)d_in[27];
    const float* n3_g  = (const float*)d_in[28], *n3_b = (const float*)d_in[29];
    float* out = (float*)d_out;

    char* p = (char*)d_ws;
    auto carve = [&](size_t bytes) -> char* {
        char* r = p;
        p += (bytes + 255) & ~(size_t)255;
        return r;
    };
    unsigned short* wt8     = (unsigned short*)carve((size_t)8 * D * D * 2);
    unsigned short* wt_sqkv = wt8;                       // saq, sak, sav contiguous
    unsigned short* wt_sao  = wt8 + (size_t)3 * D * D;
    unsigned short* wt_cqkv = wt8 + (size_t)4 * D * D;   // caq, cak, cav contiguous
    unsigned short* wt_cao  = wt8 + (size_t)7 * D * D;
    unsigned short* wt_ff1  = (unsigned short*)carve((size_t)D * DFF * 2);
    unsigned short* wt_ff2  = (unsigned short*)carve((size_t)DFF * D * 2);
    unsigned short* encb    = (unsigned short*)carve((size_t)M * D * 2);
    unsigned short* hb      = (unsigned short*)carve((size_t)M * D * 2);
    unsigned short* qbuf    = (unsigned short*)carve((size_t)M * D * 2);
    unsigned short* kbuf    = (unsigned short*)carve((size_t)M * D * 2);
    unsigned short* vtbuf   = (unsigned short*)carve((size_t)M * D * 2);
    unsigned short* ffh     = (unsigned short*)carve((size_t)M * DFF * 2);
    float* x1 = (float*)carve((size_t)M * D * 4);
    unsigned short* abuf = hb;   // lifetimes disjoint
    float* x2 = out;             // block-2 residual in d_out; block-3 in-place

    dim3 blk(256);
    wtrans8_kernel<<<dim3(32, 32, 8), blk, 0, stream>>>(
        sa_wq, sa_wk, sa_wv, sa_wo, ca_wq, ca_wk, ca_wv, ca_wo, wt8);
    wtrans_kernel<<<dim3(DFF / 32, D / 32), blk, 0, stream>>>(ff_w1, wt_ff1, D, DFF);
    wtrans_kernel<<<dim3(D / 32, DFF / 32), blk, 0, stream>>>(ff_w2, wt_ff2, DFF, D);
    cvt_kernel<<<dim3(M * D / 1024), blk, 0, stream>>>(enc, encb, M * D);

    // ---- block 1: self-attention ----
    ln_kernel<<<dim3(M), blk, 0, stream>>>(x, n1_g, n1_b, hb);
    gemm_kernel<1><<<dim3(3 * D / 128, M / 128), blk, 0, stream>>>(
        hb, hb, wt_sqkv, sa_bq, sa_bk, sa_bv, qbuf, kbuf, vtbuf, M, 3 * D, D);
    attn4_kernel<true><<<dim3(S / 128, B * 16), blk, 0, stream>>>(qbuf, kbuf, vtbuf, abuf);
    gemm_db_kernel<<<dim3(D / 128, M / 128), blk, 0, stream>>>(
        abuf, wt_sao, sa_bo, x, x1, M, D, D, 8, 4);

    // ---- block 2: cross-attention (Q from hb, K/V from encoder) ----
    ln_kernel<<<dim3(M), blk, 0, stream>>>(x1, n2_g, n2_b, hb);
    gemm_kernel<1><<<dim3(3 * D / 128, M / 128), blk, 0, stream>>>(
        hb, encb, wt_cqkv, ca_bq, ca_bk, ca_bv, qbuf, kbuf, vtbuf, M, 3 * D, D);
    attn4_kernel<false><<<dim3(S / 128, B * 16), blk, 0, stream>>>(qbuf, kbuf, vtbuf, abuf);
    gemm_db_kernel<<<dim3(D / 128, M / 128), blk, 0, stream>>>(
        abuf, wt_cao, ca_bo, x1, x2, M, D, D, 8, 4);

    // ---- block 3: feed-forward ----
    ln_kernel<<<dim3(M), blk, 0, stream>>>(x2, n3_g, n3_b, hb);
    gemm_kernel<2><<<dim3(DFF / 128, M / 128), blk, 0, stream>>>(
        hb, hb, wt_ff1, ff_b1, nullptr, nullptr, ffh, nullptr, nullptr, M, DFF, D);
    gemm_db_kernel<<<dim3(D / 128, M / 128), blk, 0, stream>>>(
        ffh, wt_ff2, ff_b2, x2, out, M, D, DFF, 4, 8);
}

// Round 7
// 534.738 us; speedup vs baseline: 1.1325x; 1.0887x over previous
//
#include <hip/hip_runtime.h>

typedef short short8 __attribute__((ext_vector_type(8)));
typedef float f32x4 __attribute__((ext_vector_type(4)));

#define SEQ 2048
#define QSCALE 0.18033688011112042f   // 0.125 * log2(e): softmax done in base 2
#define PSHIFT 20.0f                  // fixed softmax shift (cancels in O = acc/l)
#define EXP2(x) __builtin_amdgcn_exp2f(x)

__device__ __forceinline__ unsigned short f2bf(float f) {
    unsigned int u = __builtin_bit_cast(unsigned int, f);
    unsigned int r = (u + 0x7fffu + ((u >> 16) & 1u)) >> 16;
    return (unsigned short)r;
}

// ---------------------------------------------------------------------------
// Batched weight transpose + fp32->bf16: 8 D x D weights in one launch.
// ---------------------------------------------------------------------------
__global__ __launch_bounds__(256)
void wtrans8_kernel(const float* w0, const float* w1, const float* w2, const float* w3,
                    const float* w4, const float* w5, const float* w6, const float* w7,
                    unsigned short* __restrict__ outbase)
{
    const float* Ws[8] = {w0, w1, w2, w3, w4, w5, w6, w7};
    const float* __restrict__ W = Ws[blockIdx.z];
    unsigned short* __restrict__ Wt = outbase + (size_t)blockIdx.z * 1024 * 1024;
    __shared__ float t[32][33];
    const int tx = threadIdx.x & 31;
    const int ty = threadIdx.x >> 5;
    const int nb = blockIdx.x * 32;
    const int kb = blockIdx.y * 32;
#pragma unroll
    for (int i = 0; i < 4; i++)
        t[ty + i * 8][tx] = W[(size_t)(kb + ty + i * 8) * 1024 + nb + tx];
    __syncthreads();
#pragma unroll
    for (int i = 0; i < 4; i++)
        Wt[(size_t)(nb + ty + i * 8) * 1024 + kb + tx] = f2bf(t[tx][ty + i * 8]);
}

// single weight transpose (for the two FFN shapes)
__global__ __launch_bounds__(256)
void wtrans_kernel(const float* __restrict__ W, unsigned short* __restrict__ Wt,
                   int Kd, int Nd)
{
    __shared__ float t[32][33];
    const int tx = threadIdx.x & 31;
    const int ty = threadIdx.x >> 5;
    const int nb = blockIdx.x * 32;
    const int kb = blockIdx.y * 32;
#pragma unroll
    for (int i = 0; i < 4; i++)
        t[ty + i * 8][tx] = W[(size_t)(kb + ty + i * 8) * Nd + nb + tx];
    __syncthreads();
#pragma unroll
    for (int i = 0; i < 4; i++)
        Wt[(size_t)(nb + ty + i * 8) * Kd + kb + tx] = f2bf(t[tx][ty + i * 8]);
}

// ---------------------------------------------------------------------------
// Elementwise fp32 -> bf16
// ---------------------------------------------------------------------------
__global__ __launch_bounds__(256)
void cvt_kernel(const float* __restrict__ in, unsigned short* __restrict__ out, int n)
{
    int i = (blockIdx.x * 256 + threadIdx.x) * 4;
    if (i < n) {
        float4 v = *(const float4*)(in + i);
        ushort4 o;
        o.x = f2bf(v.x); o.y = f2bf(v.y); o.z = f2bf(v.z); o.w = f2bf(v.w);
        *(ushort4*)(out + i) = o;
    }
}

// ---------------------------------------------------------------------------
// LayerNorm (torch-faithful: ddof=1, eps added to std). fp32 in -> bf16 out.
// ---------------------------------------------------------------------------
__global__ __launch_bounds__(256)
void ln_kernel(const float* __restrict__ x, const float* __restrict__ g,
               const float* __restrict__ bb, unsigned short* __restrict__ out)
{
    const int D = 1024;
    const int row = blockIdx.x;
    const float* xr = x + (size_t)row * D;
    float v[4];
    float s = 0.f, ss = 0.f;
#pragma unroll
    for (int i = 0; i < 4; i++) {
        v[i] = xr[threadIdx.x + i * 256];
        s += v[i];
        ss += v[i] * v[i];
    }
#pragma unroll
    for (int off = 1; off < 64; off <<= 1) {
        s  += __shfl_xor(s,  off, 64);
        ss += __shfl_xor(ss, off, 64);
    }
    __shared__ float red[8];
    const int wave = threadIdx.x >> 6;
    if ((threadIdx.x & 63) == 0) { red[wave] = s; red[4 + wave] = ss; }
    __syncthreads();
    s  = red[0] + red[1] + red[2] + red[3];
    ss = red[4] + red[5] + red[6] + red[7];
    float mean = s / D;
    float var  = fmaxf((ss - s * mean) / (D - 1), 0.f);
    float inv  = 1.f / (sqrtf(var) + 1e-6f);
#pragma unroll
    for (int i = 0; i < 4; i++) {
        int c = threadIdx.x + i * 256;
        out[(size_t)row * D + c] = f2bf(g[c] * (v[i] - mean) * inv + bb[c]);
    }
}

// ---------------------------------------------------------------------------
// Register-staged double-buffered GEMM (round-4-proven transport) for the
// QKV projection and FFN1 shapes. C[M,N] = A[M,K] @ Wt[N,K]^T + bias.
// 128x128 tile, BK=64, 4 waves, 2 LDS buffers. Per K-step: issue next
// tile's global_load_dwordx4 -> VGPR before compute (latency hides under
// 32 MFMA), vmcnt(0) + linear ds_write_b128 after, one barrier.
// K-loop is byte-identical to gemm_db_kernel (passing); epilogues verbatim
// from the m97 gemm_kernel (passing).
// MODE 1: projection GEMM. Section = n0>>10: 0 -> Q (from A, scaled QSCALE,
//         head layout [B,H,S,64]); 1 -> K (from A2); 2 -> V (from A2,
//         written TRANSPOSED [B,H,64,S]).
// MODE 2: relu -> bf16 row-major [M,N]    (FFN first GEMM, o0)
// ---------------------------------------------------------------------------
template <int MODE>
__global__ __launch_bounds__(256, 1)
void gemm_rs_kernel(const unsigned short* __restrict__ A,
                    const unsigned short* __restrict__ A2,
                    const unsigned short* __restrict__ Wt,
                    const float* __restrict__ b0,
                    const float* __restrict__ b1,
                    const float* __restrict__ b2,
                    unsigned short* __restrict__ o0,
                    unsigned short* __restrict__ o1,
                    unsigned short* __restrict__ o2,
                    int M, int N, int K)
{
    __shared__ unsigned short As[2][128 * 64];
    __shared__ unsigned short Bs[2][128 * 64];
    const int tid  = threadIdx.x;
    const int lane = tid & 63;
    const int wv   = tid >> 6;
    const int quad = lane >> 4;
    const int l16  = lane & 15;
    const int m0 = blockIdx.y * 128;
    const int n0 = blockIdx.x * 128;
    const int wm = (wv >> 1) << 6;
    const int wn = (wv & 1) << 6;
    const int sect = (MODE == 1) ? (n0 >> 10) : 0;
    const unsigned short* Asel = (MODE == 1 && sect != 0) ? A2 : A;

    const int rsub = lane >> 3;                    // 0..7 row within chunk
    const int cu8  = ((lane & 7) ^ rsub) * 8;      // swizzled source col (elems)
    const unsigned short* Ag = Asel + (size_t)(m0 + wv * 32 + rsub) * K + cu8;
    const unsigned short* Bg = Wt   + (size_t)(n0 + wv * 32 + rsub) * K + cu8;

    f32x4 acc[4][4];
#pragma unroll
    for (int i = 0; i < 4; i++)
#pragma unroll
        for (int j = 0; j < 4; j++) acc[i][j] = f32x4{0.f, 0.f, 0.f, 0.f};

    const int NT = K >> 6;

    short8 ar[4], br[4];   // in-flight staging registers (one tile)

    auto ldregs = [&](int t) {
        const int kb = t << 6;
#pragma unroll
        for (int r = 0; r < 4; r++) {
            ar[r] = *(const short8*)(Ag + (size_t)(r * 8) * K + kb);
            br[r] = *(const short8*)(Bg + (size_t)(r * 8) * K + kb);
        }
    };
    auto wrlds = [&](int b) {
#pragma unroll
        for (int r = 0; r < 4; r++) {
            *(short8*)&As[b][(wv * 4 + r) * 512 + lane * 8] = ar[r];
            *(short8*)&Bs[b][(wv * 4 + r) * 512 + lane * 8] = br[r];
        }
    };

    // prologue: tile 0 -> regs -> LDS[0]
    ldregs(0);
    asm volatile("s_waitcnt vmcnt(0)" ::: "memory");
    wrlds(0);
    asm volatile("s_waitcnt lgkmcnt(0)" ::: "memory");
    __builtin_amdgcn_s_barrier();

    for (int i = 0; i < NT; i++) {
        const int cur = i & 1;
        if (i + 1 < NT) ldregs(i + 1);   // issue early: latency under compute

#pragma unroll
        for (int ks = 0; ks < 2; ks++) {
            short8 af[4], bfr[4];
#pragma unroll
            for (int mi = 0; mi < 4; mi++)
                af[mi] = *(const short8*)(&As[cur][(wm + mi * 16 + l16) * 64 +
                             (((ks * 4 + quad) ^ (l16 & 7)) * 8)]);
#pragma unroll
            for (int ni = 0; ni < 4; ni++)
                bfr[ni] = *(const short8*)(&Bs[cur][(wn + ni * 16 + l16) * 64 +
                             (((ks * 4 + quad) ^ (l16 & 7)) * 8)]);
#pragma unroll
            for (int mi = 0; mi < 4; mi++)
#pragma unroll
                for (int ni = 0; ni < 4; ni++)
                    acc[mi][ni] = __builtin_amdgcn_mfma_f32_16x16x32_bf16(
                        af[mi], bfr[ni], acc[mi][ni], 0, 0, 0);
        }

        if (i + 1 < NT) {
            asm volatile("s_waitcnt vmcnt(0)" ::: "memory");
            wrlds(cur ^ 1);
            asm volatile("s_waitcnt lgkmcnt(0)" ::: "memory");
            __builtin_amdgcn_s_barrier();
        }
    }

    if (MODE == 1) {
        const float* bias = (sect == 0) ? b0 : ((sect == 1) ? b1 : b2);
        if (sect == 2) {
            // V: write transposed [B,H,64,S], 4 consecutive s packed per store
#pragma unroll
            for (int mi = 0; mi < 4; mi++)
#pragma unroll
                for (int ni = 0; ni < 4; ni++) {
                    const int cc = (n0 + wn + ni * 16 + l16) & 1023;
                    const int h = cc >> 6, d = cc & 63;
                    const float bv = bias[cc];
                    const int rowg = m0 + wm + mi * 16 + quad * 4;
                    const int b = rowg >> 11, s = rowg & 2047;
                    ushort4 o4;
                    o4.x = f2bf(acc[mi][ni][0] + bv);
                    o4.y = f2bf(acc[mi][ni][1] + bv);
                    o4.z = f2bf(acc[mi][ni][2] + bv);
                    o4.w = f2bf(acc[mi][ni][3] + bv);
                    *(ushort4*)&o2[((size_t)(b * 16 + h) * 64 + d) * SEQ + s] = o4;
                }
        } else {
            unsigned short* dst = (sect == 0) ? o0 : o1;
            const float scl = (sect == 0) ? QSCALE : 1.0f;
#pragma unroll
            for (int mi = 0; mi < 4; mi++)
#pragma unroll
                for (int ni = 0; ni < 4; ni++) {
                    const int cc = (n0 + wn + ni * 16 + l16) & 1023;
                    const int h = cc >> 6, d = cc & 63;
                    const float bv = bias[cc];
#pragma unroll
                    for (int r = 0; r < 4; r++) {
                        const int rowg = m0 + wm + mi * 16 + quad * 4 + r;
                        const int b = rowg >> 11, s = rowg & 2047;
                        float v = (acc[mi][ni][r] + bv) * scl;
                        dst[((size_t)(b * 16 + h) * SEQ + s) * 64 + d] = f2bf(v);
                    }
                }
        }
    } else {
#pragma unroll
        for (int mi = 0; mi < 4; mi++)
#pragma unroll
            for (int ni = 0; ni < 4; ni++) {
                const int colg = n0 + wn + ni * 16 + l16;
                const float bv = b0[colg];
#pragma unroll
                for (int r = 0; r < 4; r++) {
                    const int rowg = m0 + wm + mi * 16 + quad * 4 + r;
                    float v = acc[mi][ni][r] + bv;
                    o0[(size_t)rowg * N + colg] = f2bf(fmaxf(v, 0.f));
                }
            }
    }
}

// ---------------------------------------------------------------------------
// Register-staged double-buffered GEMM for the N=1024 shapes (round-4 WIN:
// reg-staging >> global_load_lds at 1-2 blocks/CU).
// C[M,N] = A[M,K] @ Wt[N,K]^T + bias + res   (fp32 out, fused residual)
// 128x128 tile, BK=64, 4 waves, 2 LDS buffers. Per K-step: issue next tile's
// global_load_dwordx4 -> VGPR before compute (latency hides under 32 MFMA),
// vmcnt(0) + linear ds_write_b128 after, one barrier.
// XCD rectangle partition (cm x cn tiles per XCD): FETCH 143 -> 57 MB.
// LDS reads XOR-swizzled; swizzle pre-applied to global source addr.
// ---------------------------------------------------------------------------
__global__ __launch_bounds__(256, 1)
void gemm_db_kernel(const unsigned short* __restrict__ A,
                    const unsigned short* __restrict__ Wt,
                    const float* __restrict__ b0,
                    const float* __restrict__ res,
                    float* __restrict__ outf,
                    int M, int N, int K, int cm, int cn)
{
    __shared__ unsigned short As[2][128 * 64];
    __shared__ unsigned short Bs[2][128 * 64];
    const int tid  = threadIdx.x;
    const int lane = tid & 63;
    const int wv   = tid >> 6;
    const int quad = lane >> 4;
    const int l16  = lane & 15;
    // XCD partition: id%8 == XCD (round-robin dispatch heuristic)
    const int NX  = gridDim.x;
    const int id  = blockIdx.y * NX + blockIdx.x;
    const int xcd = id & 7, slot = id >> 3;
    const int ngx = NX / cn;                 // #col-groups of XCD rectangles
    const int rg = xcd / ngx, cg = xcd - rg * ngx;
    const int m0 = (rg * cm + (slot % cm)) * 128;
    const int n0 = (cg * cn + (slot / cm)) * 128;
    const int wm = (wv >> 1) << 6;
    const int wn = (wv & 1) << 6;

    const int rsub = lane >> 3;                    // 0..7 row within chunk
    const int cu8  = ((lane & 7) ^ rsub) * 8;      // swizzled source col (elems)
    const unsigned short* Ag = A  + (size_t)(m0 + wv * 32 + rsub) * K + cu8;
    const unsigned short* Bg = Wt + (size_t)(n0 + wv * 32 + rsub) * K + cu8;

    f32x4 acc[4][4];
#pragma unroll
    for (int i = 0; i < 4; i++)
#pragma unroll
        for (int j = 0; j < 4; j++) acc[i][j] = f32x4{0.f, 0.f, 0.f, 0.f};

    const int NT = K >> 6;

    short8 ar[4], br[4];   // in-flight staging registers (one tile)

    auto ldregs = [&](int t) {
        const int kb = t << 6;
#pragma unroll
        for (int r = 0; r < 4; r++) {
            ar[r] = *(const short8*)(Ag + (size_t)(r * 8) * K + kb);
            br[r] = *(const short8*)(Bg + (size_t)(r * 8) * K + kb);
        }
    };
    auto wrlds = [&](int b) {
#pragma unroll
        for (int r = 0; r < 4; r++) {
            *(short8*)&As[b][(wv * 4 + r) * 512 + lane * 8] = ar[r];
            *(short8*)&Bs[b][(wv * 4 + r) * 512 + lane * 8] = br[r];
        }
    };

    // prologue: tile 0 -> regs -> LDS[0]
    ldregs(0);
    asm volatile("s_waitcnt vmcnt(0)" ::: "memory");
    wrlds(0);
    asm volatile("s_waitcnt lgkmcnt(0)" ::: "memory");
    __builtin_amdgcn_s_barrier();

    for (int i = 0; i < NT; i++) {
        const int cur = i & 1;
        if (i + 1 < NT) ldregs(i + 1);   // issue early: latency under compute

        // compute buffer cur: 2 K-slices x 16 MFMA
#pragma unroll
        for (int ks = 0; ks < 2; ks++) {
            short8 af[4], bfr[4];
#pragma unroll
            for (int mi = 0; mi < 4; mi++)
                af[mi] = *(const short8*)(&As[cur][(wm + mi * 16 + l16) * 64 +
                             (((ks * 4 + quad) ^ (l16 & 7)) * 8)]);
#pragma unroll
            for (int ni = 0; ni < 4; ni++)
                bfr[ni] = *(const short8*)(&Bs[cur][(wn + ni * 16 + l16) * 64 +
                             (((ks * 4 + quad) ^ (l16 & 7)) * 8)]);
#pragma unroll
            for (int mi = 0; mi < 4; mi++)
#pragma unroll
                for (int ni = 0; ni < 4; ni++)
                    acc[mi][ni] = __builtin_amdgcn_mfma_f32_16x16x32_bf16(
                        af[mi], bfr[ni], acc[mi][ni], 0, 0, 0);
        }

        if (i + 1 < NT) {
            // regs arrived during compute; publish to the other buffer
            asm volatile("s_waitcnt vmcnt(0)" ::: "memory");
            wrlds(cur ^ 1);
            asm volatile("s_waitcnt lgkmcnt(0)" ::: "memory");
            __builtin_amdgcn_s_barrier();   // buffer cur^1 ready for all
        }
    }

    // epilogue: bias + fused residual, fp32 out
#pragma unroll
    for (int mi = 0; mi < 4; mi++)
#pragma unroll
        for (int ni = 0; ni < 4; ni++) {
            const int colg = n0 + wn + ni * 16 + l16;
            const float bv = b0[colg];
#pragma unroll
            for (int r = 0; r < 4; r++) {
                const int rowg = m0 + wm + mi * 16 + quad * 4 + r;
                outf[(size_t)rowg * N + colg] =
                    acc[mi][ni][r] + bv + res[(size_t)rowg * N + colg];
            }
        }
}

// ---------------------------------------------------------------------------
// Flash attention v4 (round-4 known-good): 128 queries/block (32/wave).
// Q (pre-scaled), K: [B,H,S,64]; VT: [B,H,64,S]; O: [B,S,1024] bf16.
// Fixed-shift base-2 softmax; register prefetch of next K/V tile; Ps
// XOR-swizzled. Causal: blockIdx remapped so co-resident block pairs have
// constant total work (kills the straggler imbalance).
// ---------------------------------------------------------------------------
template <bool CAUSAL>
__global__ __launch_bounds__(256, 2)
void attn4_kernel(const unsigned short* __restrict__ Q,
                  const unsigned short* __restrict__ K,
                  const unsigned short* __restrict__ VT,
                  unsigned short* __restrict__ O)
{
    __shared__ unsigned short Ks[128 * 72];
    __shared__ unsigned short Vt[64 * 136];
    __shared__ unsigned short Ps[4][32 * 136];
    __shared__ float sumS[4][32];
    const int tid  = threadIdx.x;
    const int lane = tid & 63;
    const int wave = tid >> 6;
    const int quad = lane >> 4;
    const int l16  = lane & 15;
    const int bh = blockIdx.y;
    // causal: pair heavy with light so each CU's two blocks sum to 17 tiles
    const int qb = (CAUSAL && (bh & 16)) ? (15 - (int)blockIdx.x) : (int)blockIdx.x;
    const int q0 = qb * 128;
    const size_t baseK = (size_t)bh * SEQ * 64;
    const size_t baseV = (size_t)bh * 64 * SEQ;

    short8 aq[2][2];
#pragma unroll
    for (int qs = 0; qs < 2; qs++) {
        const unsigned short* qp =
            Q + baseK + (size_t)(q0 + wave * 32 + qs * 16 + l16) * 64 + quad * 8;
        aq[qs][0] = *(const short8*)(qp);
        aq[qs][1] = *(const short8*)(qp + 32);
    }
    f32x4 acc[4][2];   // [mi(d)][qs]: O^T row d=mi*16+quad*4+r, col q=l16
#pragma unroll
    for (int i = 0; i < 4; i++)
#pragma unroll
        for (int j = 0; j < 2; j++) acc[i][j] = f32x4{0.f, 0.f, 0.f, 0.f};
    float lsum[2][4] = {{0.f, 0.f, 0.f, 0.f}, {0.f, 0.f, 0.f, 0.f}};

    const int nkb = CAUSAL ? (qb + 1) : (SEQ / 128);
    const int krow = tid >> 1;
    const int kc   = (tid & 1) * 32;
    const int vrow = tid >> 2;
    const int vc   = (tid & 3) * 32;
    const unsigned short* kg = K  + baseK + (size_t)krow * 64 + kc;
    const unsigned short* vg = VT + baseV + (size_t)vrow * SEQ + vc;

    short8 kr0 = *(const short8*)(kg),      kr1 = *(const short8*)(kg + 8);
    short8 kr2 = *(const short8*)(kg + 16), kr3 = *(const short8*)(kg + 24);
    short8 vr0 = *(const short8*)(vg),      vr1 = *(const short8*)(vg + 8);
    short8 vr2 = *(const short8*)(vg + 16), vr3 = *(const short8*)(vg + 24);

    for (int kb = 0; kb < nkb; kb++) {
        __syncthreads();
        *(short8*)&Ks[krow * 72 + kc]      = kr0;
        *(short8*)&Ks[krow * 72 + kc + 8]  = kr1;
        *(short8*)&Ks[krow * 72 + kc + 16] = kr2;
        *(short8*)&Ks[krow * 72 + kc + 24] = kr3;
        *(short8*)&Vt[vrow * 136 + vc]      = vr0;
        *(short8*)&Vt[vrow * 136 + vc + 8]  = vr1;
        *(short8*)&Vt[vrow * 136 + vc + 16] = vr2;
        *(short8*)&Vt[vrow * 136 + vc + 24] = vr3;
        if (kb + 1 < nkb) {
            const unsigned short* kg2 = kg + (size_t)(kb + 1) * 128 * 64;
            const unsigned short* vg2 = vg + (size_t)(kb + 1) * 128;
            kr0 = *(const short8*)(kg2);      kr1 = *(const short8*)(kg2 + 8);
            kr2 = *(const short8*)(kg2 + 16); kr3 = *(const short8*)(kg2 + 24);
            vr0 = *(const short8*)(vg2);      vr1 = *(const short8*)(vg2 + 8);
            vr2 = *(const short8*)(vg2 + 16); vr3 = *(const short8*)(vg2 + 24);
        }
        __syncthreads();

        const bool maskTile = CAUSAL && (kb == nkb - 1);
#pragma unroll
        for (int qs = 0; qs < 2; qs++) {
            f32x4 scf[8];
#pragma unroll
            for (int nt = 0; nt < 8; nt++) {
                f32x4 z = f32x4{0.f, 0.f, 0.f, 0.f};
#pragma unroll
                for (int c = 0; c < 2; c++) {
                    short8 bk = *(const short8*)(&Ks[(nt * 16 + l16) * 72 + c * 32 + quad * 8]);
                    z = __builtin_amdgcn_mfma_f32_16x16x32_bf16(aq[qs][c], bk, z, 0, 0, 0);
                }
                scf[nt] = z;
            }
            if (maskTile) {
                const int qg = q0 + wave * 32 + qs * 16 + quad * 4;
                const int k0 = kb * 128;
#pragma unroll
                for (int nt = 0; nt < 8; nt++) {
                    const int kg_ = k0 + nt * 16 + l16;
#pragma unroll
                    for (int r = 0; r < 4; r++)
                        if (kg_ > qg + r) scf[nt][r] = -1e9f;
                }
            }
#pragma unroll
            for (int nt = 0; nt < 8; nt++)
#pragma unroll
                for (int r = 0; r < 4; r++) {
                    float pv = EXP2(scf[nt][r] - PSHIFT);
                    lsum[qs][r] += pv;
                    Ps[wave][(qs * 16 + quad * 4 + r) * 136 +
                             ((nt * 16 + l16) ^ (quad * 8))] = f2bf(pv);
                }
        }
        // O^T += V^T @ P^T, both operands contiguous b128; Vt reads shared
        const int pswz = 8 * (quad ^ ((l16 >> 2) & 3));
#pragma unroll
        for (int c = 0; c < 4; c++) {
            short8 av[4];
#pragma unroll
            for (int mi = 0; mi < 4; mi++)
                av[mi] = *(const short8*)(&Vt[(mi * 16 + l16) * 136 + c * 32 + quad * 8]);
#pragma unroll
            for (int qs = 0; qs < 2; qs++) {
                short8 bp = *(const short8*)(&Ps[wave][(qs * 16 + l16) * 136 + c * 32 + pswz]);
#pragma unroll
                for (int mi = 0; mi < 4; mi++)
                    acc[mi][qs] = __builtin_amdgcn_mfma_f32_16x16x32_bf16(av[mi], bp, acc[mi][qs], 0, 0, 0);
            }
        }
    }
#pragma unroll
    for (int qs = 0; qs < 2; qs++)
#pragma unroll
        for (int r = 0; r < 4; r++) {
#pragma unroll
            for (int off = 1; off < 16; off <<= 1)
                lsum[qs][r] += __shfl_xor(lsum[qs][r], off, 64);
        }
    if (l16 == 0) {
#pragma unroll
        for (int qs = 0; qs < 2; qs++)
#pragma unroll
            for (int r = 0; r < 4; r++)
                sumS[wave][qs * 16 + quad * 4 + r] = lsum[qs][r];
    }
    __syncthreads();
    const int b = bh >> 4, h = bh & 15;
#pragma unroll
    for (int qs = 0; qs < 2; qs++) {
        const float rcpL = 1.f / sumS[wave][qs * 16 + l16];
        const int qg = q0 + wave * 32 + qs * 16 + l16;
#pragma unroll
        for (int mi = 0; mi < 4; mi++) {
            ushort4 o4;
            o4.x = f2bf(acc[mi][qs][0] * rcpL);
            o4.y = f2bf(acc[mi][qs][1] * rcpL);
            o4.z = f2bf(acc[mi][qs][2] * rcpL);
            o4.w = f2bf(acc[mi][qs][3] * rcpL);
            *(ushort4*)&O[(size_t)(b * SEQ + qg) * 1024 + h * 64 + mi * 16 + quad * 4] = o4;
        }
    }
}

// ---------------------------------------------------------------------------
extern "C" void kernel_launch(void* const* d_in, const int* in_sizes, int n_in,
                              void* d_out, int out_size, void* d_ws, size_t ws_size,
                              hipStream_t stream)
{
    (void)in_sizes; (void)n_in; (void)out_size; (void)ws_size;
    const int B = 2, S = SEQ, D = 1024, DFF = 4096;
    const int M = B * S;  // 4096

    const float* x     = (const float*)d_in[0];
    const float* enc   = (const float*)d_in[1];
    const float* sa_wq = (const float*)d_in[4],  *sa_bq = (const float*)d_in[5];
    const float* sa_wk = (const float*)d_in[6],  *sa_bk = (const float*)d_in[7];
    const float* sa_wv = (const float*)d_in[8],  *sa_bv = (const float*)d_in[9];
    const float* sa_wo = (const float*)d_in[10], *sa_bo = (const float*)d_in[11];
    const float* ca_wq = (const float*)d_in[12], *ca_bq = (const float*)d_in[13];
    const float* ca_wk = (const float*)d_in[14], *ca_bk = (const float*)d_in[15];
    const float* ca_wv = (const float*)d_in[16], *ca_bv = (const float*)d_in[17];
    const float* ca_wo = (const float*)d_in[18], *ca_bo = (const float*)d_in[19];
    const float* ff_w1 = (const float*)d_in[20], *ff_b1 = (const float*)d_in[21];
    const float* ff_w2 = (const float*)d_in[22], *ff_b2 = (const float*)d_in[23];
    const float* n1_g  = (const float*)d_in[24], *n1_b = (const float*)d_in[25];
    const float* n2_g  = (const float*)d_in[26], *n2_b = (const float*)d_in[27];
    const float* n3_g  = (const float*)d_in[28], *n3_b = (const float*)d_in[29];
    float* out = (float*)d_out;

    char* p = (char*)d_ws;
    auto carve = [&](size_t bytes) -> char* {
        char* r = p;
        p += (bytes + 255) & ~(size_t)255;
        return r;
    };
    unsigned short* wt8     = (unsigned short*)carve((size_t)8 * D * D * 2);
    unsigned short* wt_sqkv = wt8;                       // saq, sak, sav contiguous
    unsigned short* wt_sao  = wt8 + (size_t)3 * D * D;
    unsigned short* wt_cqkv = wt8 + (size_t)4 * D * D;   // caq, cak, cav contiguous
    unsigned short* wt_cao  = wt8 + (size_t)7 * D * D;
    unsigned short* wt_ff1  = (unsigned short*)carve((size_t)D * DFF * 2);
    unsigned short* wt_ff2  = (unsigned short*)carve((size_t)DFF * D * 2);
    unsigned short* encb    = (unsigned short*)carve((size_t)M * D * 2);
    unsigned short* hb      = (unsigned short*)carve((size_t)M * D * 2);
    unsigned short* qbuf    = (unsigned short*)carve((size_t)M * D * 2);
    unsigned short* kbuf    = (unsigned short*)carve((size_t)M * D * 2);
    unsigned short* vtbuf   = (unsigned short*)carve((size_t)M * D * 2);
    unsigned short* ffh     = (unsigned short*)carve((size_t)M * DFF * 2);
    float* x1 = (float*)carve((size_t)M * D * 4);
    unsigned short* abuf = hb;   // lifetimes disjoint
    float* x2 = out;             // block-2 residual in d_out; block-3 in-place

    dim3 blk(256);
    wtrans8_kernel<<<dim3(32, 32, 8), blk, 0, stream>>>(
        sa_wq, sa_wk, sa_wv, sa_wo, ca_wq, ca_wk, ca_wv, ca_wo, wt8);
    wtrans_kernel<<<dim3(DFF / 32, D / 32), blk, 0, stream>>>(ff_w1, wt_ff1, D, DFF);
    wtrans_kernel<<<dim3(D / 32, DFF / 32), blk, 0, stream>>>(ff_w2, wt_ff2, DFF, D);
    cvt_kernel<<<dim3(M * D / 1024), blk, 0, stream>>>(enc, encb, M * D);

    // ---- block 1: self-attention ----
    ln_kernel<<<dim3(M), blk, 0, stream>>>(x, n1_g, n1_b, hb);
    gemm_rs_kernel<1><<<dim3(3 * D / 128, M / 128), blk, 0, stream>>>(
        hb, hb, wt_sqkv, sa_bq, sa_bk, sa_bv, qbuf, kbuf, vtbuf, M, 3 * D, D);
    attn4_kernel<true><<<dim3(S / 128, B * 16), blk, 0, stream>>>(qbuf, kbuf, vtbuf, abuf);
    gemm_db_kernel<<<dim3(D / 128, M / 128), blk, 0, stream>>>(
        abuf, wt_sao, sa_bo, x, x1, M, D, D, 8, 4);

    // ---- block 2: cross-attention (Q from hb, K/V from encoder) ----
    ln_kernel<<<dim3(M), blk, 0, stream>>>(x1, n2_g, n2_b, hb);
    gemm_rs_kernel<1><<<dim3(3 * D / 128, M / 128), blk, 0, stream>>>(
        hb, encb, wt_cqkv, ca_bq, ca_bk, ca_bv, qbuf, kbuf, vtbuf, M, 3 * D, D);
    attn4_kernel<false><<<dim3(S / 128, B * 16), blk, 0, stream>>>(qbuf, kbuf, vtbuf, abuf);
    gemm_db_kernel<<<dim3(D / 128, M / 128), blk, 0, stream>>>(
        abuf, wt_cao, ca_bo, x1, x2, M, D, D, 8, 4);

    // ---- block 3: feed-forward ----
    ln_kernel<<<dim3(M), blk, 0, stream>>>(x2, n3_g, n3_b, hb);
    gemm_rs_kernel<2><<<dim3(DFF / 128, M / 128), blk, 0, stream>>>(
        hb, hb, wt_ff1, ff_b1, nullptr, nullptr, ffh, nullptr, nullptr, M, DFF, D);
    gemm_db_kernel<<<dim3(D / 128, M / 128), blk, 0, stream>>>(
        ffh, wt_ff2, ff_b2, x2, out, M, D, DFF, 4, 8);
}